// Round 11
// baseline (1413.653 us; speedup 1.0000x reference)
//
#include <hip/hip_runtime.h>
#include <hip/hip_bf16.h>

// GNN: 5-layer GCN on MI355X. Round 11: cache-aware CSR (column-blocked edge order).
// r10 profile: 3x spmm_bf = 54% of total, FETCH 806MB vs 50MB table => ~50% L2 hit on
// random gather, bound by L2-miss path (~3.6 TB/s). Fix: sort each row's edges by
// column-block (col>>11, 25 blocks x 2MB source) via stable 2-key counting sort
// (per-(row,cb) buckets + per-row prefix, no atomic-order dependence). All concurrent
// waves then sweep the table coherently -> working set ~2-4MB -> L2-resident.
// SpMM/GEMM kernels unchanged from r10 (counted-vmcnt pipeline, XOR swizzle, etc).

#define SCAN_CHUNK 512
#define BM 128
#define BN 128
#define BK 64
#define NB 25          // column blocks (col >> 11), 50000 -> cb in [0,24]

typedef __attribute__((ext_vector_type(4))) float f32x4;
typedef __attribute__((ext_vector_type(8))) __bf16 bf16x8;
typedef __attribute__((ext_vector_type(8))) short s16x8;

__device__ __forceinline__ bf16x8 as_bf(s16x8 v) { union { s16x8 s; bf16x8 b; } u; u.s = v; return u.b; }
__device__ __forceinline__ ushort f2bf(float f) {
    uint u = __float_as_uint(f);
    return (ushort)((u + 0x7FFFu + ((u >> 16) & 1u)) >> 16);   // RNE
}
__device__ __forceinline__ float bf2f(ushort s) { return __uint_as_float(((uint)s) << 16); }

#define GLL16(g, l)                                                                 \
    __builtin_amdgcn_global_load_lds((const __attribute__((address_space(1))) void*)(g), \
                                     (__attribute__((address_space(3))) void*)(l), 16, 0, 0)

#define STAGE_TILE8(k0, base)                                                       \
    _Pragma("unroll")                                                               \
    for (int i = 0; i < 2; ++i) {                                                   \
        int ar = row0 + arow_off + i * 64;                                          \
        if (ar >= M) ar = M - 1;                                                    \
        GLL16(A + (size_t)ar * 512 + (k0) + acol, &lds[(base) + (w * 8 + i * 64) * BK]); \
        GLL16(Bt + (size_t)(col0 + arow_off + i * 64) * 512 + (k0) + acol,          \
              &lds[(base) + 8192 + (w * 8 + i * 64) * BK]);                         \
    }

#define COMPUTE_TILE8(base)                                                         \
    _Pragma("unroll")                                                               \
    for (int s = 0; s < 2; ++s) {                                                   \
        int cswz = (((s * 4 + (l >> 4)) ^ (l & 7)) << 3);                           \
        bf16x8 af[4], bfr[2];                                                       \
        _Pragma("unroll")                                                           \
        for (int m = 0; m < 4; ++m)                                                 \
            af[m] = as_bf(*(const s16x8*)&lds[(base) + (wr + m * 16 + (l & 15)) * BK + cswz]); \
        _Pragma("unroll")                                                           \
        for (int n = 0; n < 2; ++n)                                                 \
            bfr[n] = as_bf(*(const s16x8*)&lds[(base) + 8192 + (wc + n * 16 + (l & 15)) * BK + cswz]); \
        _Pragma("unroll")                                                           \
        for (int m = 0; m < 4; ++m)                                                 \
            _Pragma("unroll")                                                       \
            for (int n = 0; n < 2; ++n)                                             \
                acc[m][n] = __builtin_amdgcn_mfma_f32_16x16x32_bf16(af[m], bfr[n], acc[m][n], 0, 0, 0); \
    }

#define KLOOP_PIPELINED()                                                           \
    STAGE_TILE8(0, 0);                                                              \
    int base = 0;                                                                   \
    _Pragma("unroll 1")                                                             \
    for (int t = 0; t < 8; ++t) {                                                   \
        if (t < 7) {                                                                \
            STAGE_TILE8((t + 1) * BK, base ^ 16384);                                \
            asm volatile("s_waitcnt vmcnt(4)" ::: "memory");                        \
        } else {                                                                    \
            asm volatile("s_waitcnt vmcnt(0)" ::: "memory");                        \
        }                                                                           \
        __builtin_amdgcn_s_barrier();                                               \
        __builtin_amdgcn_sched_barrier(0);                                          \
        COMPUTE_TILE8(base);                                                        \
        __builtin_amdgcn_sched_barrier(0);                                          \
        __builtin_amdgcn_s_barrier();                                               \
        base ^= 16384;                                                              \
    }

// ---------------- support GEMM: C[M,512]bf16 = A[M,512]bf16 @ Bt[512,512]bf16^T ------
__global__ __launch_bounds__(512) void gemm_sup(const ushort* __restrict__ A,
                                                const ushort* __restrict__ Bt,
                                                ushort* __restrict__ C, int M) {
    __shared__ ushort lds[32768];
    int tid = threadIdx.x;
    int w = tid >> 6, l = tid & 63;
    int row0 = blockIdx.y * BM, col0 = blockIdx.x * BN;
    int wr = (w >> 2) * 64, wc = (w & 3) * 32;
    f32x4 acc[4][2] = {};
    int arow_off = w * 8 + (l >> 3);
    int acol = (((l & 7) ^ (l >> 3)) << 3);

    KLOOP_PIPELINED();

    int crow = (l >> 4) * 4, ccol = l & 15;
#pragma unroll
    for (int m = 0; m < 4; ++m)
#pragma unroll
        for (int n = 0; n < 2; ++n) {
            int gc = col0 + wc + n * 16 + ccol;
#pragma unroll
            for (int r = 0; r < 4; ++r) {
                int gr = row0 + wr + m * 16 + crow + r;
                if (gr < M) C[(size_t)gr * 512 + gc] = f2bf(acc[m][n][r]);
            }
        }
}

// ---------------- fused layer-3: partial = (relu(g@W3) + tra3) @ (0.5*W4) ------------
__global__ __launch_bounds__(512) void gemm3_w4(const ushort* __restrict__ A,
                                                const ushort* __restrict__ Bt,
                                                const float* __restrict__ T,
                                                const float* __restrict__ W4,
                                                float* __restrict__ sup4p, int M) {
    __shared__ ushort lds[32768];
    int tid = threadIdx.x;
    int w = tid >> 6, l = tid & 63;
    int row0 = blockIdx.y * BM, col0 = blockIdx.x * BN;
    int wr = (w >> 2) * 64, wc = (w & 3) * 32;
    int crow = (l >> 4) * 4, ccol = l & 15;

    bf16x8 w4f;
    {
        s16x8 tmp;
#pragma unroll
        for (int kk = 0; kk < 8; ++kk) {
            int gk = col0 + (w & 3) * 32 + ((l >> 4) << 3) + kk;
            float v = (ccol < 10 && gk < 2000) ? 0.5f * W4[(size_t)gk * 10 + ccol] : 0.f;
            tmp[kk] = (short)f2bf(v);
        }
        w4f = as_bf(tmp);
    }

    f32x4 acc[4][2] = {};
    int arow_off = w * 8 + (l >> 3);
    int acol = (((l & 7) ^ (l >> 3)) << 3);

    KLOOP_PIPELINED();

    ushort* actS = lds;

    __syncthreads();
#pragma unroll
    for (int m = 0; m < 4; ++m)
#pragma unroll
        for (int n = 0; n < 2; ++n) {
            int cl = wc + n * 16 + ccol;
            int cch = cl >> 3, clo = cl & 7;
#pragma unroll
            for (int r = 0; r < 4; ++r) {
                int rl = wr + m * 16 + crow + r;
                actS[rl * 128 + (((cch ^ (rl & 7)) << 3) | clo)] = f2bf(fmaxf(acc[m][n][r], 0.f));
            }
        }
    __syncthreads();

    f32x4 acc2[4] = {};
    {
        int chunk = (w & 3) * 4 + (l >> 4);
#pragma unroll
        for (int m = 0; m < 4; ++m) {
            int row = wr + m * 16 + ccol;
            bf16x8 af = as_bf(*(const s16x8*)&actS[row * 128 + ((chunk ^ (row & 7)) << 3)]);
            acc2[m] = __builtin_amdgcn_mfma_f32_16x16x32_bf16(af, w4f, acc2[m], 0, 0, 0);
        }
    }
    __syncthreads();

    {
        int r_off = tid >> 5;
        int c4 = (tid & 31) * 4;
        int chunk = (tid & 31) >> 1;
        int lo = (tid & 1) * 4;
#pragma unroll
        for (int p = 0; p < 8; ++p) {
            int rl = p * 16 + r_off;
            int gr = row0 + rl;
            int gcb = col0 + c4;
            ushort4 h;
            if (gr < M && gcb + 3 < 2000) {
                float4 tv = *(const float4*)(T + (size_t)gr * 2000 + gcb);
                h.x = f2bf(tv.x); h.y = f2bf(tv.y); h.z = f2bf(tv.z); h.w = f2bf(tv.w);
            } else {
                float e[4];
#pragma unroll
                for (int i = 0; i < 4; ++i)
                    e[i] = (gr < M && gcb + i < 2000) ? T[(size_t)gr * 2000 + gcb + i] : 0.f;
                h.x = f2bf(e[0]); h.y = f2bf(e[1]); h.z = f2bf(e[2]); h.w = f2bf(e[3]);
            }
            *(ushort4*)&actS[rl * 128 + ((chunk ^ (rl & 7)) << 3) + lo] = h;
        }
    }
    __syncthreads();

    {
        int chunk = (w & 3) * 4 + (l >> 4);
#pragma unroll
        for (int m = 0; m < 4; ++m) {
            int row = wr + m * 16 + ccol;
            bf16x8 af = as_bf(*(const s16x8*)&actS[row * 128 + ((chunk ^ (row & 7)) << 3)]);
            acc2[m] = __builtin_amdgcn_mfma_f32_16x16x32_bf16(af, w4f, acc2[m], 0, 0, 0);
        }
    }
    __syncthreads();

    float* redS = (float*)lds;   // [4][128][16]
    {
        int q = w & 3;
#pragma unroll
        for (int m = 0; m < 4; ++m)
#pragma unroll
            for (int r = 0; r < 4; ++r) {
                int row = wr + m * 16 + crow + r;
                redS[(q * 128 + row) * 16 + ccol] = acc2[m][r];
            }
    }
    __syncthreads();
    {
        float* dst = sup4p + (size_t)blockIdx.x * ((size_t)M * 10);
#pragma unroll
        for (int p = 0; p < 4; ++p) {
            int o = p * 512 + tid;
            int row = o >> 4, col = o & 15;
            int gr = row0 + row;
            if (col < 10 && gr < M) {
                float s = redS[(0 * 128 + row) * 16 + col] + redS[(1 * 128 + row) * 16 + col]
                        + redS[(2 * 128 + row) * 16 + col] + redS[(3 * 128 + row) * 16 + col];
                dst[(size_t)gr * 10 + col] = s;
            }
        }
    }
}

// ---------------- sum 16 partial slots -> sup4 ----------------
__global__ __launch_bounds__(256) void sup4_reduce(const float* __restrict__ P,
                                                   float* __restrict__ O, int n) {
    int i = blockIdx.x * 256 + threadIdx.x;
    if (i >= n) return;
    float s = 0.f;
#pragma unroll
    for (int j = 0; j < 16; ++j) s += P[(size_t)j * n + i];
    O[i] = s;
}

// ---------------- conversions ----------------
__global__ __launch_bounds__(256) void cvt4(const float* __restrict__ s,
                                            ushort* __restrict__ d, long n4) {
    long i = (long)blockIdx.x * 256 + threadIdx.x;
    if (i >= n4) return;
    float4 v = ((const float4*)s)[i];
    ushort4 o = { f2bf(v.x), f2bf(v.y), f2bf(v.z), f2bf(v.w) };
    ((ushort4*)d)[i] = o;
}

__global__ __launch_bounds__(256) void cvt_wt(const float* __restrict__ W,
                                              ushort* __restrict__ Wt,
                                              int Ksrc, int Nsrc, int Npad) {
    int i = blockIdx.x * 256 + threadIdx.x;
    if (i >= Npad * 512) return;
    int n = i >> 9, k = i & 511;
    float v = (k < Ksrc && n < Nsrc) ? W[(size_t)k * Nsrc + n] : 0.f;
    Wt[i] = f2bf(v);
}

// ---------------- CSR build (column-blocked stable order) ----------------
__global__ __launch_bounds__(256) void csr_count(const int* __restrict__ rows,
                                                 int* __restrict__ cnt, int E) {
    int e = blockIdx.x * 256 + threadIdx.x;
    if (e < E) atomicAdd(&cnt[rows[e]], 1);
}

// per-(row, colblock) counts
__global__ __launch_bounds__(256) void cb_count(const int* __restrict__ rows,
                                                const int* __restrict__ cols,
                                                int* __restrict__ cnt25, int E) {
    int e = blockIdx.x * 256 + threadIdx.x;
    if (e < E) atomicAdd(&cnt25[rows[e] * NB + (cols[e] >> 11)], 1);
}

// per-row prefix over 25 colblock buckets -> bucket start pointers (cur25)
__global__ __launch_bounds__(256) void rowscan(const int* __restrict__ rowptr,
                                               const int* __restrict__ cnt25,
                                               int* __restrict__ cur25, int n) {
    int r = blockIdx.x * 256 + threadIdx.x;
    if (r >= n) return;
    int base = rowptr[r];
#pragma unroll
    for (int cb = 0; cb < NB; ++cb) {
        int c = cnt25[r * NB + cb];
        cur25[r * NB + cb] = base;
        base += c;
    }
}

__global__ __launch_bounds__(256) void scan1(const int* __restrict__ cnt,
                                             int* __restrict__ csum, int n) {
    __shared__ int red[256];
    int base = blockIdx.x * SCAN_CHUNK;
    int t = threadIdx.x;
    int s = 0;
    if (base + t < n) s += cnt[base + t];
    if (base + t + 256 < n) s += cnt[base + t + 256];
    red[t] = s;
    __syncthreads();
    for (int off = 128; off; off >>= 1) {
        if (t < off) red[t] += red[t + off];
        __syncthreads();
    }
    if (t == 0) csum[blockIdx.x] = red[0];
}

__global__ void scan2(int* csum, int nch) {
    if (threadIdx.x == 0 && blockIdx.x == 0) {
        int acc = 0;
        for (int i = 0; i < nch; ++i) { int v = csum[i]; csum[i] = acc; acc += v; }
    }
}

__global__ __launch_bounds__(256) void scan3(const int* __restrict__ cnt,
                                             const int* __restrict__ csum,
                                             int* __restrict__ rowptr, int n, int E) {
    __shared__ int sm[SCAN_CHUNK];
    int base = blockIdx.x * SCAN_CHUNK;
    int t = threadIdx.x;
    for (int i = t; i < SCAN_CHUNK; i += 256) sm[i] = (base + i < n) ? cnt[base + i] : 0;
    __syncthreads();
    for (int off = 1; off < SCAN_CHUNK; off <<= 1) {
        int i0 = t, i1 = t + 256;
        int v0 = (i0 >= off) ? sm[i0 - off] : 0;
        int v1 = (i1 >= off) ? sm[i1 - off] : 0;
        __syncthreads();
        sm[i0] += v0;
        sm[i1] += v1;
        __syncthreads();
    }
    int off0 = csum[blockIdx.x];
    for (int i = t; i < SCAN_CHUNK; i += 256)
        if (base + i < n) rowptr[base + i] = off0 + (i ? sm[i - 1] : 0);
    if (blockIdx.x == 0 && t == 0) rowptr[n] = E;
}

// scatter into (row, colblock) buckets: within-row edges end up colblock-ordered
__global__ __launch_bounds__(256) void csr_fill(const int* __restrict__ rows,
                                                const int* __restrict__ cols,
                                                const float* __restrict__ vals,
                                                int* __restrict__ cur25,
                                                int2* __restrict__ edges, int E) {
    int e = blockIdx.x * 256 + threadIdx.x;
    if (e >= E) return;
    int c = cols[e];
    int p = atomicAdd(&cur25[rows[e] * NB + (c >> 11)], 1);
    edges[p] = make_int2(c, __float_as_int(vals[e]));
}

// ---------------- SpMM gather, bf16 source [nrows,512]: wave per row, 4-edge unroll --
__global__ __launch_bounds__(256) void spmm_bf(const int* __restrict__ rowptr,
                                               const int2* __restrict__ edges,
                                               const ushort* __restrict__ S,
                                               const float* __restrict__ T,
                                               ushort* __restrict__ O,
                                               int nrows, int domix) {
    int wid = (int)((blockIdx.x * 256 + threadIdx.x) >> 6);
    int lane = threadIdx.x & 63;
    if (wid >= nrows) return;
    int beg = rowptr[wid], end = rowptr[wid + 1];
    float acc[8] = {0.f, 0.f, 0.f, 0.f, 0.f, 0.f, 0.f, 0.f};
    int e = beg;
    for (; e + 3 < end; e += 4) {
        int2 e0 = edges[e], e1 = edges[e + 1], e2 = edges[e + 2], e3 = edges[e + 3];
        float v0 = __int_as_float(e0.y), v1 = __int_as_float(e1.y);
        float v2 = __int_as_float(e2.y), v3 = __int_as_float(e3.y);
        s16x8 a = ((const s16x8*)(S + (size_t)e0.x * 512))[lane];
        s16x8 b = ((const s16x8*)(S + (size_t)e1.x * 512))[lane];
        s16x8 c = ((const s16x8*)(S + (size_t)e2.x * 512))[lane];
        s16x8 d = ((const s16x8*)(S + (size_t)e3.x * 512))[lane];
#pragma unroll
        for (int j = 0; j < 8; ++j)
            acc[j] += v0 * bf2f((ushort)a[j]) + v1 * bf2f((ushort)b[j])
                    + v2 * bf2f((ushort)c[j]) + v3 * bf2f((ushort)d[j]);
    }
    for (; e + 1 < end; e += 2) {
        int2 e0 = edges[e], e1 = edges[e + 1];
        float v0 = __int_as_float(e0.y), v1 = __int_as_float(e1.y);
        s16x8 a = ((const s16x8*)(S + (size_t)e0.x * 512))[lane];
        s16x8 b = ((const s16x8*)(S + (size_t)e1.x * 512))[lane];
#pragma unroll
        for (int j = 0; j < 8; ++j)
            acc[j] += v0 * bf2f((ushort)a[j]) + v1 * bf2f((ushort)b[j]);
    }
    if (e < end) {
        int2 e0 = edges[e];
        float v0 = __int_as_float(e0.y);
        s16x8 a = ((const s16x8*)(S + (size_t)e0.x * 512))[lane];
#pragma unroll
        for (int j = 0; j < 8; ++j)
            acc[j] += v0 * bf2f((ushort)a[j]);
    }
    int c0 = lane * 8;
    float res[8];
    if (domix) {
        float tv[8] = {0.f, 0.f, 0.f, 0.f, 0.f, 0.f, 0.f, 0.f};
        const float* trow = T + (size_t)wid * 500;
        if (c0 + 8 <= 500) {
            float4 t0 = *(const float4*)(trow + c0);
            float4 t1 = *(const float4*)(trow + c0 + 4);
            tv[0] = t0.x; tv[1] = t0.y; tv[2] = t0.z; tv[3] = t0.w;
            tv[4] = t1.x; tv[5] = t1.y; tv[6] = t1.z; tv[7] = t1.w;
        } else {
#pragma unroll
            for (int j = 0; j < 8; ++j)
                if (c0 + j < 500) tv[j] = trow[c0 + j];
        }
#pragma unroll
        for (int j = 0; j < 8; ++j)
            res[j] = (c0 + j < 500) ? (0.5f * fmaxf(acc[j], 0.f) + 0.5f * tv[j]) : 0.f;
    } else {
#pragma unroll
        for (int j = 0; j < 8; ++j)
            res[j] = (c0 + j < 500) ? acc[j] : 0.f;
    }
    s16x8 o;
#pragma unroll
    for (int j = 0; j < 8; ++j) o[j] = (short)f2bf(res[j]);
    ((s16x8*)(O + (size_t)wid * 512))[lane] = o;
}

// ---------------- SpMM gather, D=10 f32; optional fused mix+@W5 epilogue -------------
__global__ __launch_bounds__(256) void spmm10(const int* __restrict__ rowptr,
                                              const int2* __restrict__ edges,
                                              const float* __restrict__ S,
                                              const float* __restrict__ T,
                                              const float* __restrict__ W5,
                                              float* __restrict__ O, int nrows) {
    int g = (int)((blockIdx.x * 256 + threadIdx.x) >> 4);
    int t = threadIdx.x & 15;
    if (g >= nrows || t >= 10) return;
    int beg = rowptr[g], end = rowptr[g + 1];
    float acc = 0.f;
    for (int e = beg; e < end; ++e) {
        int2 ed = edges[e];
        acc += __int_as_float(ed.y) * S[(size_t)ed.x * 10 + t];
    }
    if (W5) {
        float m = 0.5f * fmaxf(acc, 0.f) + 0.5f * T[(size_t)g * 10 + t];
        float s5 = 0.f;
#pragma unroll
        for (int i = 0; i < 10; ++i)
            s5 += __shfl(m, i, 16) * W5[i * 10 + t];
        O[(size_t)g * 10 + t] = s5;
    } else {
        O[(size_t)g * 10 + t] = acc;
    }
}

extern "C" void kernel_launch(void* const* d_in, const int* in_sizes, int n_in,
                              void* d_out, int out_size, void* d_ws, size_t ws_size,
                              hipStream_t stream) {
    const float* x    = (const float*)d_in[0];
    const int*   ar   = (const int*)d_in[1];
    const int*   ac   = (const int*)d_in[2];
    const float* av   = (const float*)d_in[3];
    const float* tra1 = (const float*)d_in[4];
    const float* tra2 = (const float*)d_in[5];
    const float* tra3 = (const float*)d_in[6];
    const float* z    = (const float*)d_in[7];
    const float* W1   = (const float*)d_in[8];
    const float* W2   = (const float*)d_in[9];
    const float* W3   = (const float*)d_in[10];
    const float* W4   = (const float*)d_in[11];
    const float* W5   = (const float*)d_in[12];

    const int E = in_sizes[1];
    const int N = in_sizes[7] / 10;   // 50000
    const int NCH = (N + SCAN_CHUNK - 1) / SCAN_CHUNK;

    ushort* Abf    = (ushort*)d_ws;                     // [N,512] bf16
    ushort* Sbf    = Abf + (size_t)N * 512;             // [N,512] bf16
    ushort* Wt1    = Sbf + (size_t)N * 512;             // [512,512] bf16
    ushort* Wt2    = Wt1 + 512 * 512;                   // [512,512] bf16
    ushort* Wt3    = Wt2 + 512 * 512;                   // [2048,512] bf16
    float*  sup4   = (float*)(Wt3 + 2048 * 512);        // [N,10] f32
    float*  sup5   = sup4 + (size_t)N * 10;             // [N,10] f32
    float*  sup4p  = sup5 + (size_t)N * 10;             // [16][N*10] f32 partials (32 MB)
    int2*   edges  = (int2*)(sup4p + (size_t)16 * N * 10); // [E]
    int*    rowptr = (int*)(edges + E);                 // [N+1]
    int*    cnt    = rowptr + (N + 1);                  // [N]
    int*    csum   = cnt + N;                           // [NCH]
    int*    cnt25  = csum + NCH;                        // [N*NB]
    int*    cur25  = cnt25 + N * NB;                    // [N*NB]
    float*  out    = (float*)d_out;

    dim3 blk(256);
    dim3 blk8(512);

    // ---- all conversions upfront (independent) ----
    cvt4<<<(int)(((long)N * 512 / 4 + 255) / 256), blk, 0, stream>>>(x, Abf, (long)N * 512 / 4);
    cvt_wt<<<(512 * 512 + 255) / 256, blk, 0, stream>>>(W1, Wt1, 512, 500, 512);
    cvt_wt<<<(512 * 512 + 255) / 256, blk, 0, stream>>>(W2, Wt2, 500, 500, 512);
    cvt_wt<<<(2048 * 512 + 255) / 256, blk, 0, stream>>>(W3, Wt3, 500, 2000, 2048);

    // ---- CSR build (stable column-blocked order) ----
    hipMemsetAsync(cnt, 0, (size_t)N * sizeof(int), stream);
    hipMemsetAsync(cnt25, 0, (size_t)N * NB * sizeof(int), stream);
    csr_count<<<(E + 255) / 256, blk, 0, stream>>>(ar, cnt, E);
    cb_count<<<(E + 255) / 256, blk, 0, stream>>>(ar, ac, cnt25, E);
    scan1<<<NCH, blk, 0, stream>>>(cnt, csum, N);
    scan2<<<1, 64, 0, stream>>>(csum, NCH);
    scan3<<<NCH, blk, 0, stream>>>(cnt, csum, rowptr, N, E);
    rowscan<<<(N + 255) / 256, blk, 0, stream>>>(rowptr, cnt25, cur25, N);
    csr_fill<<<(E + 255) / 256, blk, 0, stream>>>(ar, ac, av, cur25, edges, E);

    const int spmm_blocks   = (N * 64 + 255) / 256;
    const int spmm10_blocks = (N * 16 + 255) / 256;

    // ---- Layer 1: Sbf = Abf@W1t; Abf = mix(spmm(Sbf), tra1)
    {
        dim3 g(4, (N + BM - 1) / BM);
        gemm_sup<<<g, blk8, 0, stream>>>(Abf, Wt1, Sbf, N);
    }
    spmm_bf<<<spmm_blocks, blk, 0, stream>>>(rowptr, edges, Sbf, tra1, Abf, N, 1);

    // ---- Layer 2: Sbf = Abf@W2t; Abf(m2) = mix(spmm(Sbf), tra2)
    {
        dim3 g(4, (N + BM - 1) / BM);
        gemm_sup<<<g, blk8, 0, stream>>>(Abf, Wt2, Sbf, N);
    }
    spmm_bf<<<spmm_blocks, blk, 0, stream>>>(rowptr, edges, Sbf, tra2, Abf, N, 1);

    // ---- Layer 3 (spmm-first, fused): Sbf(g) = spmm(m2) raw;
    //      sup4p[16 slots] = (relu(g@W3)+tra3)@(0.5*W4) partials; sup4 = sum
    spmm_bf<<<spmm_blocks, blk, 0, stream>>>(rowptr, edges, Abf, nullptr, Sbf, N, 0);
    {
        dim3 g(16, (N + BM - 1) / BM);
        gemm3_w4<<<g, blk8, 0, stream>>>(Sbf, Wt3, tra3, W4, sup4p, N);
    }
    sup4_reduce<<<(N * 10 + 255) / 256, blk, 0, stream>>>(sup4p, sup4, N * 10);

    // ---- Layer 4+5a: sup5 = (mix(spmm(sup4), z)) @ W5  (fused epilogue)
    spmm10<<<spmm10_blocks, blk, 0, stream>>>(rowptr, edges, sup4, z, W5, sup5, N);

    // ---- Layer 5b: out = spmm(sup5) raw
    spmm10<<<spmm10_blocks, blk, 0, stream>>>(rowptr, edges, sup5, nullptr, nullptr, out, N);
}

// Round 12
// 1362.618 us; speedup vs baseline: 1.0375x; 1.0375x over previous
//
#include <hip/hip_runtime.h>
#include <hip/hip_bf16.h>

// GNN: 5-layer GCN on MI355X. Round 12:
// - REVERT r11 col-block edge sort (null on spmm, +65us build cost; bucket size 1.3
//   and wave drift smeared the coherence band to ~18MB >> 4MB per-XCD L2).
// - spmm_bf -> spmm_bfs: D-SLICED gather. 8 passes x 64 cols (one 128B line/edge/pass;
//   slice table 6.4MB ~ per-XCD L2, ~4x line reuse within a pass). Single launch with
//   pass in grid.y (slowest-varying -> pass-major dispatch; correctness is
//   order-independent, locality emerges from scheduling). Wave=row: 8 groups x 8
//   lanes, group g takes edges beg+g+8k (8 concurrent line gathers), shfl_xor
//   combine, group 0 mixes + writes the 128B output slice.
// Unchanged from r10: counted-vmcnt MFMA K-loop, XOR swizzle, mix-through-W4,
// LDS partial combine, CSR counting-sort build.

#define SCAN_CHUNK 512
#define BM 128
#define BN 128
#define BK 64
#define NSLICE 8       // 512 cols / 64

typedef __attribute__((ext_vector_type(4))) float f32x4;
typedef __attribute__((ext_vector_type(8))) __bf16 bf16x8;
typedef __attribute__((ext_vector_type(8))) short s16x8;

__device__ __forceinline__ bf16x8 as_bf(s16x8 v) { union { s16x8 s; bf16x8 b; } u; u.s = v; return u.b; }
__device__ __forceinline__ ushort f2bf(float f) {
    uint u = __float_as_uint(f);
    return (ushort)((u + 0x7FFFu + ((u >> 16) & 1u)) >> 16);   // RNE
}
__device__ __forceinline__ float bf2f(ushort s) { return __uint_as_float(((uint)s) << 16); }

#define GLL16(g, l)                                                                 \
    __builtin_amdgcn_global_load_lds((const __attribute__((address_space(1))) void*)(g), \
                                     (__attribute__((address_space(3))) void*)(l), 16, 0, 0)

#define STAGE_TILE8(k0, base)                                                       \
    _Pragma("unroll")                                                               \
    for (int i = 0; i < 2; ++i) {                                                   \
        int ar = row0 + arow_off + i * 64;                                          \
        if (ar >= M) ar = M - 1;                                                    \
        GLL16(A + (size_t)ar * 512 + (k0) + acol, &lds[(base) + (w * 8 + i * 64) * BK]); \
        GLL16(Bt + (size_t)(col0 + arow_off + i * 64) * 512 + (k0) + acol,          \
              &lds[(base) + 8192 + (w * 8 + i * 64) * BK]);                         \
    }

#define COMPUTE_TILE8(base)                                                         \
    _Pragma("unroll")                                                               \
    for (int s = 0; s < 2; ++s) {                                                   \
        int cswz = (((s * 4 + (l >> 4)) ^ (l & 7)) << 3);                           \
        bf16x8 af[4], bfr[2];                                                       \
        _Pragma("unroll")                                                           \
        for (int m = 0; m < 4; ++m)                                                 \
            af[m] = as_bf(*(const s16x8*)&lds[(base) + (wr + m * 16 + (l & 15)) * BK + cswz]); \
        _Pragma("unroll")                                                           \
        for (int n = 0; n < 2; ++n)                                                 \
            bfr[n] = as_bf(*(const s16x8*)&lds[(base) + 8192 + (wc + n * 16 + (l & 15)) * BK + cswz]); \
        _Pragma("unroll")                                                           \
        for (int m = 0; m < 4; ++m)                                                 \
            _Pragma("unroll")                                                       \
            for (int n = 0; n < 2; ++n)                                             \
                acc[m][n] = __builtin_amdgcn_mfma_f32_16x16x32_bf16(af[m], bfr[n], acc[m][n], 0, 0, 0); \
    }

#define KLOOP_PIPELINED()                                                           \
    STAGE_TILE8(0, 0);                                                              \
    int base = 0;                                                                   \
    _Pragma("unroll 1")                                                             \
    for (int t = 0; t < 8; ++t) {                                                   \
        if (t < 7) {                                                                \
            STAGE_TILE8((t + 1) * BK, base ^ 16384);                                \
            asm volatile("s_waitcnt vmcnt(4)" ::: "memory");                        \
        } else {                                                                    \
            asm volatile("s_waitcnt vmcnt(0)" ::: "memory");                        \
        }                                                                           \
        __builtin_amdgcn_s_barrier();                                               \
        __builtin_amdgcn_sched_barrier(0);                                          \
        COMPUTE_TILE8(base);                                                        \
        __builtin_amdgcn_sched_barrier(0);                                          \
        __builtin_amdgcn_s_barrier();                                               \
        base ^= 16384;                                                              \
    }

// ---------------- support GEMM: C[M,512]bf16 = A[M,512]bf16 @ Bt[512,512]bf16^T ------
__global__ __launch_bounds__(512) void gemm_sup(const ushort* __restrict__ A,
                                                const ushort* __restrict__ Bt,
                                                ushort* __restrict__ C, int M) {
    __shared__ ushort lds[32768];
    int tid = threadIdx.x;
    int w = tid >> 6, l = tid & 63;
    int row0 = blockIdx.y * BM, col0 = blockIdx.x * BN;
    int wr = (w >> 2) * 64, wc = (w & 3) * 32;
    f32x4 acc[4][2] = {};
    int arow_off = w * 8 + (l >> 3);
    int acol = (((l & 7) ^ (l >> 3)) << 3);

    KLOOP_PIPELINED();

    int crow = (l >> 4) * 4, ccol = l & 15;
#pragma unroll
    for (int m = 0; m < 4; ++m)
#pragma unroll
        for (int n = 0; n < 2; ++n) {
            int gc = col0 + wc + n * 16 + ccol;
#pragma unroll
            for (int r = 0; r < 4; ++r) {
                int gr = row0 + wr + m * 16 + crow + r;
                if (gr < M) C[(size_t)gr * 512 + gc] = f2bf(acc[m][n][r]);
            }
        }
}

// ---------------- fused layer-3: partial = (relu(g@W3) + tra3) @ (0.5*W4) ------------
__global__ __launch_bounds__(512) void gemm3_w4(const ushort* __restrict__ A,
                                                const ushort* __restrict__ Bt,
                                                const float* __restrict__ T,
                                                const float* __restrict__ W4,
                                                float* __restrict__ sup4p, int M) {
    __shared__ ushort lds[32768];
    int tid = threadIdx.x;
    int w = tid >> 6, l = tid & 63;
    int row0 = blockIdx.y * BM, col0 = blockIdx.x * BN;
    int wr = (w >> 2) * 64, wc = (w & 3) * 32;
    int crow = (l >> 4) * 4, ccol = l & 15;

    bf16x8 w4f;
    {
        s16x8 tmp;
#pragma unroll
        for (int kk = 0; kk < 8; ++kk) {
            int gk = col0 + (w & 3) * 32 + ((l >> 4) << 3) + kk;
            float v = (ccol < 10 && gk < 2000) ? 0.5f * W4[(size_t)gk * 10 + ccol] : 0.f;
            tmp[kk] = (short)f2bf(v);
        }
        w4f = as_bf(tmp);
    }

    f32x4 acc[4][2] = {};
    int arow_off = w * 8 + (l >> 3);
    int acol = (((l & 7) ^ (l >> 3)) << 3);

    KLOOP_PIPELINED();

    ushort* actS = lds;

    __syncthreads();
#pragma unroll
    for (int m = 0; m < 4; ++m)
#pragma unroll
        for (int n = 0; n < 2; ++n) {
            int cl = wc + n * 16 + ccol;
            int cch = cl >> 3, clo = cl & 7;
#pragma unroll
            for (int r = 0; r < 4; ++r) {
                int rl = wr + m * 16 + crow + r;
                actS[rl * 128 + (((cch ^ (rl & 7)) << 3) | clo)] = f2bf(fmaxf(acc[m][n][r], 0.f));
            }
        }
    __syncthreads();

    f32x4 acc2[4] = {};
    {
        int chunk = (w & 3) * 4 + (l >> 4);
#pragma unroll
        for (int m = 0; m < 4; ++m) {
            int row = wr + m * 16 + ccol;
            bf16x8 af = as_bf(*(const s16x8*)&actS[row * 128 + ((chunk ^ (row & 7)) << 3)]);
            acc2[m] = __builtin_amdgcn_mfma_f32_16x16x32_bf16(af, w4f, acc2[m], 0, 0, 0);
        }
    }
    __syncthreads();

    {
        int r_off = tid >> 5;
        int c4 = (tid & 31) * 4;
        int chunk = (tid & 31) >> 1;
        int lo = (tid & 1) * 4;
#pragma unroll
        for (int p = 0; p < 8; ++p) {
            int rl = p * 16 + r_off;
            int gr = row0 + rl;
            int gcb = col0 + c4;
            ushort4 h;
            if (gr < M && gcb + 3 < 2000) {
                float4 tv = *(const float4*)(T + (size_t)gr * 2000 + gcb);
                h.x = f2bf(tv.x); h.y = f2bf(tv.y); h.z = f2bf(tv.z); h.w = f2bf(tv.w);
            } else {
                float e[4];
#pragma unroll
                for (int i = 0; i < 4; ++i)
                    e[i] = (gr < M && gcb + i < 2000) ? T[(size_t)gr * 2000 + gcb + i] : 0.f;
                h.x = f2bf(e[0]); h.y = f2bf(e[1]); h.z = f2bf(e[2]); h.w = f2bf(e[3]);
            }
            *(ushort4*)&actS[rl * 128 + ((chunk ^ (rl & 7)) << 3) + lo] = h;
        }
    }
    __syncthreads();

    {
        int chunk = (w & 3) * 4 + (l >> 4);
#pragma unroll
        for (int m = 0; m < 4; ++m) {
            int row = wr + m * 16 + ccol;
            bf16x8 af = as_bf(*(const s16x8*)&actS[row * 128 + ((chunk ^ (row & 7)) << 3)]);
            acc2[m] = __builtin_amdgcn_mfma_f32_16x16x32_bf16(af, w4f, acc2[m], 0, 0, 0);
        }
    }
    __syncthreads();

    float* redS = (float*)lds;   // [4][128][16]
    {
        int q = w & 3;
#pragma unroll
        for (int m = 0; m < 4; ++m)
#pragma unroll
            for (int r = 0; r < 4; ++r) {
                int row = wr + m * 16 + crow + r;
                redS[(q * 128 + row) * 16 + ccol] = acc2[m][r];
            }
    }
    __syncthreads();
    {
        float* dst = sup4p + (size_t)blockIdx.x * ((size_t)M * 10);
#pragma unroll
        for (int p = 0; p < 4; ++p) {
            int o = p * 512 + tid;
            int row = o >> 4, col = o & 15;
            int gr = row0 + row;
            if (col < 10 && gr < M) {
                float s = redS[(0 * 128 + row) * 16 + col] + redS[(1 * 128 + row) * 16 + col]
                        + redS[(2 * 128 + row) * 16 + col] + redS[(3 * 128 + row) * 16 + col];
                dst[(size_t)gr * 10 + col] = s;
            }
        }
    }
}

// ---------------- sum 16 partial slots -> sup4 ----------------
__global__ __launch_bounds__(256) void sup4_reduce(const float* __restrict__ P,
                                                   float* __restrict__ O, int n) {
    int i = blockIdx.x * 256 + threadIdx.x;
    if (i >= n) return;
    float s = 0.f;
#pragma unroll
    for (int j = 0; j < 16; ++j) s += P[(size_t)j * n + i];
    O[i] = s;
}

// ---------------- conversions ----------------
__global__ __launch_bounds__(256) void cvt4(const float* __restrict__ s,
                                            ushort* __restrict__ d, long n4) {
    long i = (long)blockIdx.x * 256 + threadIdx.x;
    if (i >= n4) return;
    float4 v = ((const float4*)s)[i];
    ushort4 o = { f2bf(v.x), f2bf(v.y), f2bf(v.z), f2bf(v.w) };
    ((ushort4*)d)[i] = o;
}

__global__ __launch_bounds__(256) void cvt_wt(const float* __restrict__ W,
                                              ushort* __restrict__ Wt,
                                              int Ksrc, int Nsrc, int Npad) {
    int i = blockIdx.x * 256 + threadIdx.x;
    if (i >= Npad * 512) return;
    int n = i >> 9, k = i & 511;
    float v = (k < Ksrc && n < Nsrc) ? W[(size_t)k * Nsrc + n] : 0.f;
    Wt[i] = f2bf(v);
}

// ---------------- CSR build: count / scan / fill (simple r10 order) ----------------
__global__ __launch_bounds__(256) void csr_count(const int* __restrict__ rows,
                                                 int* __restrict__ cnt, int E) {
    int e = blockIdx.x * 256 + threadIdx.x;
    if (e < E) atomicAdd(&cnt[rows[e]], 1);
}

__global__ __launch_bounds__(256) void scan1(const int* __restrict__ cnt,
                                             int* __restrict__ csum, int n) {
    __shared__ int red[256];
    int base = blockIdx.x * SCAN_CHUNK;
    int t = threadIdx.x;
    int s = 0;
    if (base + t < n) s += cnt[base + t];
    if (base + t + 256 < n) s += cnt[base + t + 256];
    red[t] = s;
    __syncthreads();
    for (int off = 128; off; off >>= 1) {
        if (t < off) red[t] += red[t + off];
        __syncthreads();
    }
    if (t == 0) csum[blockIdx.x] = red[0];
}

__global__ void scan2(int* csum, int nch) {
    if (threadIdx.x == 0 && blockIdx.x == 0) {
        int acc = 0;
        for (int i = 0; i < nch; ++i) { int v = csum[i]; csum[i] = acc; acc += v; }
    }
}

__global__ __launch_bounds__(256) void scan3(const int* __restrict__ cnt,
                                             const int* __restrict__ csum,
                                             int* __restrict__ rowptr, int n, int E) {
    __shared__ int sm[SCAN_CHUNK];
    int base = blockIdx.x * SCAN_CHUNK;
    int t = threadIdx.x;
    for (int i = t; i < SCAN_CHUNK; i += 256) sm[i] = (base + i < n) ? cnt[base + i] : 0;
    __syncthreads();
    for (int off = 1; off < SCAN_CHUNK; off <<= 1) {
        int i0 = t, i1 = t + 256;
        int v0 = (i0 >= off) ? sm[i0 - off] : 0;
        int v1 = (i1 >= off) ? sm[i1 - off] : 0;
        __syncthreads();
        sm[i0] += v0;
        sm[i1] += v1;
        __syncthreads();
    }
    int off0 = csum[blockIdx.x];
    for (int i = t; i < SCAN_CHUNK; i += 256)
        if (base + i < n) rowptr[base + i] = off0 + (i ? sm[i - 1] : 0);
    if (blockIdx.x == 0 && t == 0) rowptr[n] = E;
}

__global__ __launch_bounds__(256) void csr_fill(const int* __restrict__ rows,
                                                const int* __restrict__ cols,
                                                const float* __restrict__ vals,
                                                int* __restrict__ cur,
                                                int2* __restrict__ edges, int E) {
    int e = blockIdx.x * 256 + threadIdx.x;
    if (e >= E) return;
    int p = atomicAdd(&cur[rows[e]], 1);
    edges[p] = make_int2(cols[e], __float_as_int(vals[e]));
}

// ---------------- D-sliced SpMM gather: wave=row, pass=blockIdx.y (64-col slice) -----
// Wave: 8 groups x 8 lanes. Group g handles edges beg+g+8k, each gathering the
// 128B slice [pass*64, pass*64+64) of source row col(e). shfl_xor combine over
// groups; group 0 applies mix and writes the 128B output slice.
__global__ __launch_bounds__(256) void spmm_bfs(const int* __restrict__ rowptr,
                                                const int2* __restrict__ edges,
                                                const ushort* __restrict__ S,
                                                const float* __restrict__ T,
                                                ushort* __restrict__ O,
                                                int nrows, int domix) {
    int wid = (int)((blockIdx.x * 256 + threadIdx.x) >> 6);
    if (wid >= nrows) return;
    int lane = threadIdx.x & 63;
    int g = lane >> 3, t = lane & 7;
    int c0 = blockIdx.y * 64 + t * 8;          // this lane's 8-col sub-slice
    int beg = rowptr[wid], end = rowptr[wid + 1];

    float acc[8] = {0.f, 0.f, 0.f, 0.f, 0.f, 0.f, 0.f, 0.f};
    int e = beg + g;
    for (; e + 8 < end; e += 16) {
        int2 e0 = edges[e], e1 = edges[e + 8];
        float v0 = __int_as_float(e0.y), v1 = __int_as_float(e1.y);
        s16x8 a = *(const s16x8*)(S + (size_t)e0.x * 512 + c0);
        s16x8 b = *(const s16x8*)(S + (size_t)e1.x * 512 + c0);
#pragma unroll
        for (int j = 0; j < 8; ++j)
            acc[j] += v0 * bf2f((ushort)a[j]) + v1 * bf2f((ushort)b[j]);
    }
    if (e < end) {
        int2 e0 = edges[e];
        float v0 = __int_as_float(e0.y);
        s16x8 a = *(const s16x8*)(S + (size_t)e0.x * 512 + c0);
#pragma unroll
        for (int j = 0; j < 8; ++j)
            acc[j] += v0 * bf2f((ushort)a[j]);
    }

    // combine the 8 groups (lanes with equal t)
#pragma unroll
    for (int off = 8; off <= 32; off <<= 1)
#pragma unroll
        for (int j = 0; j < 8; ++j)
            acc[j] += __shfl_xor(acc[j], off, 64);

    if (g != 0) return;
    float res[8];
    if (domix) {
        float tv[8] = {0.f, 0.f, 0.f, 0.f, 0.f, 0.f, 0.f, 0.f};
        const float* trow = T + (size_t)wid * 500;
        if (c0 + 8 <= 500) {
            float4 t0 = *(const float4*)(trow + c0);
            float4 t1 = *(const float4*)(trow + c0 + 4);
            tv[0] = t0.x; tv[1] = t0.y; tv[2] = t0.z; tv[3] = t0.w;
            tv[4] = t1.x; tv[5] = t1.y; tv[6] = t1.z; tv[7] = t1.w;
        } else {
#pragma unroll
            for (int j = 0; j < 8; ++j)
                if (c0 + j < 500) tv[j] = trow[c0 + j];
        }
#pragma unroll
        for (int j = 0; j < 8; ++j)
            res[j] = (c0 + j < 500) ? (0.5f * fmaxf(acc[j], 0.f) + 0.5f * tv[j]) : 0.f;
    } else {
#pragma unroll
        for (int j = 0; j < 8; ++j)
            res[j] = (c0 + j < 500) ? acc[j] : 0.f;
    }
    s16x8 o;
#pragma unroll
    for (int j = 0; j < 8; ++j) o[j] = (short)f2bf(res[j]);
    *(s16x8*)(O + (size_t)wid * 512 + c0) = o;
}

// ---------------- SpMM gather, D=10 f32; optional fused mix+@W5 epilogue -------------
__global__ __launch_bounds__(256) void spmm10(const int* __restrict__ rowptr,
                                              const int2* __restrict__ edges,
                                              const float* __restrict__ S,
                                              const float* __restrict__ T,
                                              const float* __restrict__ W5,
                                              float* __restrict__ O, int nrows) {
    int g = (int)((blockIdx.x * 256 + threadIdx.x) >> 4);
    int t = threadIdx.x & 15;
    if (g >= nrows || t >= 10) return;
    int beg = rowptr[g], end = rowptr[g + 1];
    float acc = 0.f;
    for (int e = beg; e < end; ++e) {
        int2 ed = edges[e];
        acc += __int_as_float(ed.y) * S[(size_t)ed.x * 10 + t];
    }
    if (W5) {
        float m = 0.5f * fmaxf(acc, 0.f) + 0.5f * T[(size_t)g * 10 + t];
        float s5 = 0.f;
#pragma unroll
        for (int i = 0; i < 10; ++i)
            s5 += __shfl(m, i, 16) * W5[i * 10 + t];
        O[(size_t)g * 10 + t] = s5;
    } else {
        O[(size_t)g * 10 + t] = acc;
    }
}

extern "C" void kernel_launch(void* const* d_in, const int* in_sizes, int n_in,
                              void* d_out, int out_size, void* d_ws, size_t ws_size,
                              hipStream_t stream) {
    const float* x    = (const float*)d_in[0];
    const int*   ar   = (const int*)d_in[1];
    const int*   ac   = (const int*)d_in[2];
    const float* av   = (const float*)d_in[3];
    const float* tra1 = (const float*)d_in[4];
    const float* tra2 = (const float*)d_in[5];
    const float* tra3 = (const float*)d_in[6];
    const float* z    = (const float*)d_in[7];
    const float* W1   = (const float*)d_in[8];
    const float* W2   = (const float*)d_in[9];
    const float* W3   = (const float*)d_in[10];
    const float* W4   = (const float*)d_in[11];
    const float* W5   = (const float*)d_in[12];

    const int E = in_sizes[1];
    const int N = in_sizes[7] / 10;   // 50000
    const int NCH = (N + SCAN_CHUNK - 1) / SCAN_CHUNK;

    ushort* Abf    = (ushort*)d_ws;                     // [N,512] bf16
    ushort* Sbf    = Abf + (size_t)N * 512;             // [N,512] bf16
    ushort* Wt1    = Sbf + (size_t)N * 512;             // [512,512] bf16
    ushort* Wt2    = Wt1 + 512 * 512;                   // [512,512] bf16
    ushort* Wt3    = Wt2 + 512 * 512;                   // [2048,512] bf16
    float*  sup4   = (float*)(Wt3 + 2048 * 512);        // [N,10] f32
    float*  sup5   = sup4 + (size_t)N * 10;             // [N,10] f32
    float*  sup4p  = sup5 + (size_t)N * 10;             // [16][N*10] f32 partials
    int2*   edges  = (int2*)(sup4p + (size_t)16 * N * 10); // [E]
    int*    rowptr = (int*)(edges + E);                 // [N+1]
    int*    cnt    = rowptr + (N + 1);                  // [N]
    int*    csum   = cnt + N;                           // [NCH]
    float*  out    = (float*)d_out;

    dim3 blk(256);
    dim3 blk8(512);

    // ---- all conversions upfront (independent) ----
    cvt4<<<(int)(((long)N * 512 / 4 + 255) / 256), blk, 0, stream>>>(x, Abf, (long)N * 512 / 4);
    cvt_wt<<<(512 * 512 + 255) / 256, blk, 0, stream>>>(W1, Wt1, 512, 500, 512);
    cvt_wt<<<(512 * 512 + 255) / 256, blk, 0, stream>>>(W2, Wt2, 500, 500, 512);
    cvt_wt<<<(2048 * 512 + 255) / 256, blk, 0, stream>>>(W3, Wt3, 500, 2000, 2048);

    // ---- CSR build ----
    hipMemsetAsync(cnt, 0, (size_t)N * sizeof(int), stream);
    csr_count<<<(E + 255) / 256, blk, 0, stream>>>(ar, cnt, E);
    scan1<<<NCH, blk, 0, stream>>>(cnt, csum, N);
    scan2<<<1, 64, 0, stream>>>(csum, NCH);
    scan3<<<NCH, blk, 0, stream>>>(cnt, csum, rowptr, N, E);
    hipMemcpyAsync(cnt, rowptr, (size_t)N * sizeof(int), hipMemcpyDeviceToDevice, stream);
    csr_fill<<<(E + 255) / 256, blk, 0, stream>>>(ar, ac, av, cnt, edges, E);

    dim3 spmm_grid((N * 64 + 255) / 256, NSLICE);
    const int spmm10_blocks = (N * 16 + 255) / 256;

    // ---- Layer 1: Sbf = Abf@W1t; Abf = mix(spmm(Sbf), tra1)
    {
        dim3 g(4, (N + BM - 1) / BM);
        gemm_sup<<<g, blk8, 0, stream>>>(Abf, Wt1, Sbf, N);
    }
    spmm_bfs<<<spmm_grid, blk, 0, stream>>>(rowptr, edges, Sbf, tra1, Abf, N, 1);

    // ---- Layer 2: Sbf = Abf@W2t; Abf(m2) = mix(spmm(Sbf), tra2)
    {
        dim3 g(4, (N + BM - 1) / BM);
        gemm_sup<<<g, blk8, 0, stream>>>(Abf, Wt2, Sbf, N);
    }
    spmm_bfs<<<spmm_grid, blk, 0, stream>>>(rowptr, edges, Sbf, tra2, Abf, N, 1);

    // ---- Layer 3 (spmm-first, fused): Sbf(g) = spmm(m2) raw;
    //      sup4p[16 slots] = (relu(g@W3)+tra3)@(0.5*W4) partials; sup4 = sum
    spmm_bfs<<<spmm_grid, blk, 0, stream>>>(rowptr, edges, Abf, nullptr, Sbf, N, 0);
    {
        dim3 g(16, (N + BM - 1) / BM);
        gemm3_w4<<<g, blk8, 0, stream>>>(Sbf, Wt3, tra3, W4, sup4p, N);
    }
    sup4_reduce<<<(N * 10 + 255) / 256, blk, 0, stream>>>(sup4p, sup4, N * 10);

    // ---- Layer 4+5a: sup5 = (mix(spmm(sup4), z)) @ W5  (fused epilogue)
    spmm10<<<spmm10_blocks, blk, 0, stream>>>(rowptr, edges, sup4, z, W5, sup5, N);

    // ---- Layer 5b: out = spmm(sup5) raw
    spmm10<<<spmm10_blocks, blk, 0, stream>>>(rowptr, edges, sup5, nullptr, nullptr, out, N);
}

// Round 13
// 1246.428 us; speedup vs baseline: 1.1342x; 1.0932x over previous
//
#include <hip/hip_runtime.h>
#include <hip/hip_bf16.h>

// GNN: 5-layer GCN on MI355X. Round 13: D-sliced SpMM, GROUP-PER-ROW decomposition.
// r12 kept FETCH at 558MB (slicing works; floor ~400MB = 50MB table x 8 XCD L2 fills)
// but went VALU-bound (66%): 8-groups-per-row gave ~4 edges/group (2x loop trips) +
// 192 shfl/wave/pass. Now: 32 groups of 8 lanes per block, each group owns ONE row's
// 64-col slice, 4-edge unroll over all its edges, no shuffles, every lane writes its
// own 16B. Per-lane instruction economics identical to the r10 unsliced kernel.
// Unchanged: counted-vmcnt MFMA K-loop, XOR swizzle, mix-through-W4, LDS partial
// combine, CSR counting-sort build, pass-major grid.y slicing.

#define SCAN_CHUNK 512
#define BM 128
#define BN 128
#define BK 64
#define NSLICE 8       // 512 cols / 64

typedef __attribute__((ext_vector_type(4))) float f32x4;
typedef __attribute__((ext_vector_type(8))) __bf16 bf16x8;
typedef __attribute__((ext_vector_type(8))) short s16x8;

__device__ __forceinline__ bf16x8 as_bf(s16x8 v) { union { s16x8 s; bf16x8 b; } u; u.s = v; return u.b; }
__device__ __forceinline__ ushort f2bf(float f) {
    uint u = __float_as_uint(f);
    return (ushort)((u + 0x7FFFu + ((u >> 16) & 1u)) >> 16);   // RNE
}
__device__ __forceinline__ float bf2f(ushort s) { return __uint_as_float(((uint)s) << 16); }

#define GLL16(g, l)                                                                 \
    __builtin_amdgcn_global_load_lds((const __attribute__((address_space(1))) void*)(g), \
                                     (__attribute__((address_space(3))) void*)(l), 16, 0, 0)

#define STAGE_TILE8(k0, base)                                                       \
    _Pragma("unroll")                                                               \
    for (int i = 0; i < 2; ++i) {                                                   \
        int ar = row0 + arow_off + i * 64;                                          \
        if (ar >= M) ar = M - 1;                                                    \
        GLL16(A + (size_t)ar * 512 + (k0) + acol, &lds[(base) + (w * 8 + i * 64) * BK]); \
        GLL16(Bt + (size_t)(col0 + arow_off + i * 64) * 512 + (k0) + acol,          \
              &lds[(base) + 8192 + (w * 8 + i * 64) * BK]);                         \
    }

#define COMPUTE_TILE8(base)                                                         \
    _Pragma("unroll")                                                               \
    for (int s = 0; s < 2; ++s) {                                                   \
        int cswz = (((s * 4 + (l >> 4)) ^ (l & 7)) << 3);                           \
        bf16x8 af[4], bfr[2];                                                       \
        _Pragma("unroll")                                                           \
        for (int m = 0; m < 4; ++m)                                                 \
            af[m] = as_bf(*(const s16x8*)&lds[(base) + (wr + m * 16 + (l & 15)) * BK + cswz]); \
        _Pragma("unroll")                                                           \
        for (int n = 0; n < 2; ++n)                                                 \
            bfr[n] = as_bf(*(const s16x8*)&lds[(base) + 8192 + (wc + n * 16 + (l & 15)) * BK + cswz]); \
        _Pragma("unroll")                                                           \
        for (int m = 0; m < 4; ++m)                                                 \
            _Pragma("unroll")                                                       \
            for (int n = 0; n < 2; ++n)                                             \
                acc[m][n] = __builtin_amdgcn_mfma_f32_16x16x32_bf16(af[m], bfr[n], acc[m][n], 0, 0, 0); \
    }

#define KLOOP_PIPELINED()                                                           \
    STAGE_TILE8(0, 0);                                                              \
    int base = 0;                                                                   \
    _Pragma("unroll 1")                                                             \
    for (int t = 0; t < 8; ++t) {                                                   \
        if (t < 7) {                                                                \
            STAGE_TILE8((t + 1) * BK, base ^ 16384);                                \
            asm volatile("s_waitcnt vmcnt(4)" ::: "memory");                        \
        } else {                                                                    \
            asm volatile("s_waitcnt vmcnt(0)" ::: "memory");                        \
        }                                                                           \
        __builtin_amdgcn_s_barrier();                                               \
        __builtin_amdgcn_sched_barrier(0);                                          \
        COMPUTE_TILE8(base);                                                        \
        __builtin_amdgcn_sched_barrier(0);                                          \
        __builtin_amdgcn_s_barrier();                                               \
        base ^= 16384;                                                              \
    }

// ---------------- support GEMM: C[M,512]bf16 = A[M,512]bf16 @ Bt[512,512]bf16^T ------
__global__ __launch_bounds__(512) void gemm_sup(const ushort* __restrict__ A,
                                                const ushort* __restrict__ Bt,
                                                ushort* __restrict__ C, int M) {
    __shared__ ushort lds[32768];
    int tid = threadIdx.x;
    int w = tid >> 6, l = tid & 63;
    int row0 = blockIdx.y * BM, col0 = blockIdx.x * BN;
    int wr = (w >> 2) * 64, wc = (w & 3) * 32;
    f32x4 acc[4][2] = {};
    int arow_off = w * 8 + (l >> 3);
    int acol = (((l & 7) ^ (l >> 3)) << 3);

    KLOOP_PIPELINED();

    int crow = (l >> 4) * 4, ccol = l & 15;
#pragma unroll
    for (int m = 0; m < 4; ++m)
#pragma unroll
        for (int n = 0; n < 2; ++n) {
            int gc = col0 + wc + n * 16 + ccol;
#pragma unroll
            for (int r = 0; r < 4; ++r) {
                int gr = row0 + wr + m * 16 + crow + r;
                if (gr < M) C[(size_t)gr * 512 + gc] = f2bf(acc[m][n][r]);
            }
        }
}

// ---------------- fused layer-3: partial = (relu(g@W3) + tra3) @ (0.5*W4) ------------
__global__ __launch_bounds__(512) void gemm3_w4(const ushort* __restrict__ A,
                                                const ushort* __restrict__ Bt,
                                                const float* __restrict__ T,
                                                const float* __restrict__ W4,
                                                float* __restrict__ sup4p, int M) {
    __shared__ ushort lds[32768];
    int tid = threadIdx.x;
    int w = tid >> 6, l = tid & 63;
    int row0 = blockIdx.y * BM, col0 = blockIdx.x * BN;
    int wr = (w >> 2) * 64, wc = (w & 3) * 32;
    int crow = (l >> 4) * 4, ccol = l & 15;

    bf16x8 w4f;
    {
        s16x8 tmp;
#pragma unroll
        for (int kk = 0; kk < 8; ++kk) {
            int gk = col0 + (w & 3) * 32 + ((l >> 4) << 3) + kk;
            float v = (ccol < 10 && gk < 2000) ? 0.5f * W4[(size_t)gk * 10 + ccol] : 0.f;
            tmp[kk] = (short)f2bf(v);
        }
        w4f = as_bf(tmp);
    }

    f32x4 acc[4][2] = {};
    int arow_off = w * 8 + (l >> 3);
    int acol = (((l & 7) ^ (l >> 3)) << 3);

    KLOOP_PIPELINED();

    ushort* actS = lds;

    __syncthreads();
#pragma unroll
    for (int m = 0; m < 4; ++m)
#pragma unroll
        for (int n = 0; n < 2; ++n) {
            int cl = wc + n * 16 + ccol;
            int cch = cl >> 3, clo = cl & 7;
#pragma unroll
            for (int r = 0; r < 4; ++r) {
                int rl = wr + m * 16 + crow + r;
                actS[rl * 128 + (((cch ^ (rl & 7)) << 3) | clo)] = f2bf(fmaxf(acc[m][n][r], 0.f));
            }
        }
    __syncthreads();

    f32x4 acc2[4] = {};
    {
        int chunk = (w & 3) * 4 + (l >> 4);
#pragma unroll
        for (int m = 0; m < 4; ++m) {
            int row = wr + m * 16 + ccol;
            bf16x8 af = as_bf(*(const s16x8*)&actS[row * 128 + ((chunk ^ (row & 7)) << 3)]);
            acc2[m] = __builtin_amdgcn_mfma_f32_16x16x32_bf16(af, w4f, acc2[m], 0, 0, 0);
        }
    }
    __syncthreads();

    {
        int r_off = tid >> 5;
        int c4 = (tid & 31) * 4;
        int chunk = (tid & 31) >> 1;
        int lo = (tid & 1) * 4;
#pragma unroll
        for (int p = 0; p < 8; ++p) {
            int rl = p * 16 + r_off;
            int gr = row0 + rl;
            int gcb = col0 + c4;
            ushort4 h;
            if (gr < M && gcb + 3 < 2000) {
                float4 tv = *(const float4*)(T + (size_t)gr * 2000 + gcb);
                h.x = f2bf(tv.x); h.y = f2bf(tv.y); h.z = f2bf(tv.z); h.w = f2bf(tv.w);
            } else {
                float e[4];
#pragma unroll
                for (int i = 0; i < 4; ++i)
                    e[i] = (gr < M && gcb + i < 2000) ? T[(size_t)gr * 2000 + gcb + i] : 0.f;
                h.x = f2bf(e[0]); h.y = f2bf(e[1]); h.z = f2bf(e[2]); h.w = f2bf(e[3]);
            }
            *(ushort4*)&actS[rl * 128 + ((chunk ^ (rl & 7)) << 3) + lo] = h;
        }
    }
    __syncthreads();

    {
        int chunk = (w & 3) * 4 + (l >> 4);
#pragma unroll
        for (int m = 0; m < 4; ++m) {
            int row = wr + m * 16 + ccol;
            bf16x8 af = as_bf(*(const s16x8*)&actS[row * 128 + ((chunk ^ (row & 7)) << 3)]);
            acc2[m] = __builtin_amdgcn_mfma_f32_16x16x32_bf16(af, w4f, acc2[m], 0, 0, 0);
        }
    }
    __syncthreads();

    float* redS = (float*)lds;   // [4][128][16]
    {
        int q = w & 3;
#pragma unroll
        for (int m = 0; m < 4; ++m)
#pragma unroll
            for (int r = 0; r < 4; ++r) {
                int row = wr + m * 16 + crow + r;
                redS[(q * 128 + row) * 16 + ccol] = acc2[m][r];
            }
    }
    __syncthreads();
    {
        float* dst = sup4p + (size_t)blockIdx.x * ((size_t)M * 10);
#pragma unroll
        for (int p = 0; p < 4; ++p) {
            int o = p * 512 + tid;
            int row = o >> 4, col = o & 15;
            int gr = row0 + row;
            if (col < 10 && gr < M) {
                float s = redS[(0 * 128 + row) * 16 + col] + redS[(1 * 128 + row) * 16 + col]
                        + redS[(2 * 128 + row) * 16 + col] + redS[(3 * 128 + row) * 16 + col];
                dst[(size_t)gr * 10 + col] = s;
            }
        }
    }
}

// ---------------- sum 16 partial slots -> sup4 ----------------
__global__ __launch_bounds__(256) void sup4_reduce(const float* __restrict__ P,
                                                   float* __restrict__ O, int n) {
    int i = blockIdx.x * 256 + threadIdx.x;
    if (i >= n) return;
    float s = 0.f;
#pragma unroll
    for (int j = 0; j < 16; ++j) s += P[(size_t)j * n + i];
    O[i] = s;
}

// ---------------- conversions ----------------
__global__ __launch_bounds__(256) void cvt4(const float* __restrict__ s,
                                            ushort* __restrict__ d, long n4) {
    long i = (long)blockIdx.x * 256 + threadIdx.x;
    if (i >= n4) return;
    float4 v = ((const float4*)s)[i];
    ushort4 o = { f2bf(v.x), f2bf(v.y), f2bf(v.z), f2bf(v.w) };
    ((ushort4*)d)[i] = o;
}

__global__ __launch_bounds__(256) void cvt_wt(const float* __restrict__ W,
                                              ushort* __restrict__ Wt,
                                              int Ksrc, int Nsrc, int Npad) {
    int i = blockIdx.x * 256 + threadIdx.x;
    if (i >= Npad * 512) return;
    int n = i >> 9, k = i & 511;
    float v = (k < Ksrc && n < Nsrc) ? W[(size_t)k * Nsrc + n] : 0.f;
    Wt[i] = f2bf(v);
}

// ---------------- CSR build: count / scan / fill ----------------
__global__ __launch_bounds__(256) void csr_count(const int* __restrict__ rows,
                                                 int* __restrict__ cnt, int E) {
    int e = blockIdx.x * 256 + threadIdx.x;
    if (e < E) atomicAdd(&cnt[rows[e]], 1);
}

__global__ __launch_bounds__(256) void scan1(const int* __restrict__ cnt,
                                             int* __restrict__ csum, int n) {
    __shared__ int red[256];
    int base = blockIdx.x * SCAN_CHUNK;
    int t = threadIdx.x;
    int s = 0;
    if (base + t < n) s += cnt[base + t];
    if (base + t + 256 < n) s += cnt[base + t + 256];
    red[t] = s;
    __syncthreads();
    for (int off = 128; off; off >>= 1) {
        if (t < off) red[t] += red[t + off];
        __syncthreads();
    }
    if (t == 0) csum[blockIdx.x] = red[0];
}

__global__ void scan2(int* csum, int nch) {
    if (threadIdx.x == 0 && blockIdx.x == 0) {
        int acc = 0;
        for (int i = 0; i < nch; ++i) { int v = csum[i]; csum[i] = acc; acc += v; }
    }
}

__global__ __launch_bounds__(256) void scan3(const int* __restrict__ cnt,
                                             const int* __restrict__ csum,
                                             int* __restrict__ rowptr, int n, int E) {
    __shared__ int sm[SCAN_CHUNK];
    int base = blockIdx.x * SCAN_CHUNK;
    int t = threadIdx.x;
    for (int i = t; i < SCAN_CHUNK; i += 256) sm[i] = (base + i < n) ? cnt[base + i] : 0;
    __syncthreads();
    for (int off = 1; off < SCAN_CHUNK; off <<= 1) {
        int i0 = t, i1 = t + 256;
        int v0 = (i0 >= off) ? sm[i0 - off] : 0;
        int v1 = (i1 >= off) ? sm[i1 - off] : 0;
        __syncthreads();
        sm[i0] += v0;
        sm[i1] += v1;
        __syncthreads();
    }
    int off0 = csum[blockIdx.x];
    for (int i = t; i < SCAN_CHUNK; i += 256)
        if (base + i < n) rowptr[base + i] = off0 + (i ? sm[i - 1] : 0);
    if (blockIdx.x == 0 && t == 0) rowptr[n] = E;
}

__global__ __launch_bounds__(256) void csr_fill(const int* __restrict__ rows,
                                                const int* __restrict__ cols,
                                                const float* __restrict__ vals,
                                                int* __restrict__ cur,
                                                int2* __restrict__ edges, int E) {
    int e = blockIdx.x * 256 + threadIdx.x;
    if (e >= E) return;
    int p = atomicAdd(&cur[rows[e]], 1);
    edges[p] = make_int2(cols[e], __float_as_int(vals[e]));
}

// ---------------- D-sliced SpMM gather, GROUP-PER-ROW ----------------
// Block = 32 groups of 8 lanes. Group owns row (blockIdx.x*32+grp)'s 64-col slice
// [blockIdx.y*64, +64); lane t owns 8 cols. 4-edge unroll; no cross-lane combine.
__global__ __launch_bounds__(256) void spmm_bfs(const int* __restrict__ rowptr,
                                                const int2* __restrict__ edges,
                                                const ushort* __restrict__ S,
                                                const float* __restrict__ T,
                                                ushort* __restrict__ O,
                                                int nrows, int domix) {
    int row = (int)((blockIdx.x * 256 + threadIdx.x) >> 3);
    if (row >= nrows) return;
    int t = threadIdx.x & 7;
    int c0 = blockIdx.y * 64 + t * 8;          // this lane's 8-col sub-slice
    int beg = rowptr[row], end = rowptr[row + 1];
    const ushort* Sc = S + c0;

    float acc[8] = {0.f, 0.f, 0.f, 0.f, 0.f, 0.f, 0.f, 0.f};
    int e = beg;
    for (; e + 3 < end; e += 4) {
        int2 e0 = edges[e], e1 = edges[e + 1], e2 = edges[e + 2], e3 = edges[e + 3];
        float v0 = __int_as_float(e0.y), v1 = __int_as_float(e1.y);
        float v2 = __int_as_float(e2.y), v3 = __int_as_float(e3.y);
        s16x8 a = *(const s16x8*)(Sc + (size_t)e0.x * 512);
        s16x8 b = *(const s16x8*)(Sc + (size_t)e1.x * 512);
        s16x8 c = *(const s16x8*)(Sc + (size_t)e2.x * 512);
        s16x8 d = *(const s16x8*)(Sc + (size_t)e3.x * 512);
#pragma unroll
        for (int j = 0; j < 8; ++j)
            acc[j] += v0 * bf2f((ushort)a[j]) + v1 * bf2f((ushort)b[j])
                    + v2 * bf2f((ushort)c[j]) + v3 * bf2f((ushort)d[j]);
    }
    for (; e < end; ++e) {
        int2 e0 = edges[e];
        float v0 = __int_as_float(e0.y);
        s16x8 a = *(const s16x8*)(Sc + (size_t)e0.x * 512);
#pragma unroll
        for (int j = 0; j < 8; ++j)
            acc[j] += v0 * bf2f((ushort)a[j]);
    }

    float res[8];
    if (domix) {
        float tv[8] = {0.f, 0.f, 0.f, 0.f, 0.f, 0.f, 0.f, 0.f};
        const float* trow = T + (size_t)row * 500;
        if (c0 + 8 <= 500) {
            float4 t0 = *(const float4*)(trow + c0);
            float4 t1 = *(const float4*)(trow + c0 + 4);
            tv[0] = t0.x; tv[1] = t0.y; tv[2] = t0.z; tv[3] = t0.w;
            tv[4] = t1.x; tv[5] = t1.y; tv[6] = t1.z; tv[7] = t1.w;
        } else {
#pragma unroll
            for (int j = 0; j < 8; ++j)
                if (c0 + j < 500) tv[j] = trow[c0 + j];
        }
#pragma unroll
        for (int j = 0; j < 8; ++j)
            res[j] = (c0 + j < 500) ? (0.5f * fmaxf(acc[j], 0.f) + 0.5f * tv[j]) : 0.f;
    } else {
#pragma unroll
        for (int j = 0; j < 8; ++j)
            res[j] = (c0 + j < 500) ? acc[j] : 0.f;
    }
    s16x8 o;
#pragma unroll
    for (int j = 0; j < 8; ++j) o[j] = (short)f2bf(res[j]);
    *(s16x8*)(O + (size_t)row * 512 + c0) = o;
}

// ---------------- SpMM gather, D=10 f32; optional fused mix+@W5 epilogue -------------
__global__ __launch_bounds__(256) void spmm10(const int* __restrict__ rowptr,
                                              const int2* __restrict__ edges,
                                              const float* __restrict__ S,
                                              const float* __restrict__ T,
                                              const float* __restrict__ W5,
                                              float* __restrict__ O, int nrows) {
    int g = (int)((blockIdx.x * 256 + threadIdx.x) >> 4);
    int t = threadIdx.x & 15;
    if (g >= nrows || t >= 10) return;
    int beg = rowptr[g], end = rowptr[g + 1];
    float acc = 0.f;
    for (int e = beg; e < end; ++e) {
        int2 ed = edges[e];
        acc += __int_as_float(ed.y) * S[(size_t)ed.x * 10 + t];
    }
    if (W5) {
        float m = 0.5f * fmaxf(acc, 0.f) + 0.5f * T[(size_t)g * 10 + t];
        float s5 = 0.f;
#pragma unroll
        for (int i = 0; i < 10; ++i)
            s5 += __shfl(m, i, 16) * W5[i * 10 + t];
        O[(size_t)g * 10 + t] = s5;
    } else {
        O[(size_t)g * 10 + t] = acc;
    }
}

extern "C" void kernel_launch(void* const* d_in, const int* in_sizes, int n_in,
                              void* d_out, int out_size, void* d_ws, size_t ws_size,
                              hipStream_t stream) {
    const float* x    = (const float*)d_in[0];
    const int*   ar   = (const int*)d_in[1];
    const int*   ac   = (const int*)d_in[2];
    const float* av   = (const float*)d_in[3];
    const float* tra1 = (const float*)d_in[4];
    const float* tra2 = (const float*)d_in[5];
    const float* tra3 = (const float*)d_in[6];
    const float* z    = (const float*)d_in[7];
    const float* W1   = (const float*)d_in[8];
    const float* W2   = (const float*)d_in[9];
    const float* W3   = (const float*)d_in[10];
    const float* W4   = (const float*)d_in[11];
    const float* W5   = (const float*)d_in[12];

    const int E = in_sizes[1];
    const int N = in_sizes[7] / 10;   // 50000
    const int NCH = (N + SCAN_CHUNK - 1) / SCAN_CHUNK;

    ushort* Abf    = (ushort*)d_ws;                     // [N,512] bf16
    ushort* Sbf    = Abf + (size_t)N * 512;             // [N,512] bf16
    ushort* Wt1    = Sbf + (size_t)N * 512;             // [512,512] bf16
    ushort* Wt2    = Wt1 + 512 * 512;                   // [512,512] bf16
    ushort* Wt3    = Wt2 + 512 * 512;                   // [2048,512] bf16
    float*  sup4   = (float*)(Wt3 + 2048 * 512);        // [N,10] f32
    float*  sup5   = sup4 + (size_t)N * 10;             // [N,10] f32
    float*  sup4p  = sup5 + (size_t)N * 10;             // [16][N*10] f32 partials
    int2*   edges  = (int2*)(sup4p + (size_t)16 * N * 10); // [E]
    int*    rowptr = (int*)(edges + E);                 // [N+1]
    int*    cnt    = rowptr + (N + 1);                  // [N]
    int*    csum   = cnt + N;                           // [NCH]
    float*  out    = (float*)d_out;

    dim3 blk(256);
    dim3 blk8(512);

    // ---- all conversions upfront (independent) ----
    cvt4<<<(int)(((long)N * 512 / 4 + 255) / 256), blk, 0, stream>>>(x, Abf, (long)N * 512 / 4);
    cvt_wt<<<(512 * 512 + 255) / 256, blk, 0, stream>>>(W1, Wt1, 512, 500, 512);
    cvt_wt<<<(512 * 512 + 255) / 256, blk, 0, stream>>>(W2, Wt2, 500, 500, 512);
    cvt_wt<<<(2048 * 512 + 255) / 256, blk, 0, stream>>>(W3, Wt3, 500, 2000, 2048);

    // ---- CSR build ----
    hipMemsetAsync(cnt, 0, (size_t)N * sizeof(int), stream);
    csr_count<<<(E + 255) / 256, blk, 0, stream>>>(ar, cnt, E);
    scan1<<<NCH, blk, 0, stream>>>(cnt, csum, N);
    scan2<<<1, 64, 0, stream>>>(csum, NCH);
    scan3<<<NCH, blk, 0, stream>>>(cnt, csum, rowptr, N, E);
    hipMemcpyAsync(cnt, rowptr, (size_t)N * sizeof(int), hipMemcpyDeviceToDevice, stream);
    csr_fill<<<(E + 255) / 256, blk, 0, stream>>>(ar, ac, av, cnt, edges, E);

    dim3 spmm_grid((N * 8 + 255) / 256, NSLICE);
    const int spmm10_blocks = (N * 16 + 255) / 256;

    // ---- Layer 1: Sbf = Abf@W1t; Abf = mix(spmm(Sbf), tra1)
    {
        dim3 g(4, (N + BM - 1) / BM);
        gemm_sup<<<g, blk8, 0, stream>>>(Abf, Wt1, Sbf, N);
    }
    spmm_bfs<<<spmm_grid, blk, 0, stream>>>(rowptr, edges, Sbf, tra1, Abf, N, 1);

    // ---- Layer 2: Sbf = Abf@W2t; Abf(m2) = mix(spmm(Sbf), tra2)
    {
        dim3 g(4, (N + BM - 1) / BM);
        gemm_sup<<<g, blk8, 0, stream>>>(Abf, Wt2, Sbf, N);
    }
    spmm_bfs<<<spmm_grid, blk, 0, stream>>>(rowptr, edges, Sbf, tra2, Abf, N, 1);

    // ---- Layer 3 (spmm-first, fused): Sbf(g) = spmm(m2) raw;
    //      sup4p[16 slots] = (relu(g@W3)+tra3)@(0.5*W4) partials; sup4 = sum
    spmm_bfs<<<spmm_grid, blk, 0, stream>>>(rowptr, edges, Abf, nullptr, Sbf, N, 0);
    {
        dim3 g(16, (N + BM - 1) / BM);
        gemm3_w4<<<g, blk8, 0, stream>>>(Sbf, Wt3, tra3, W4, sup4p, N);
    }
    sup4_reduce<<<(N * 10 + 255) / 256, blk, 0, stream>>>(sup4p, sup4, N * 10);

    // ---- Layer 4+5a: sup5 = (mix(spmm(sup4), z)) @ W5  (fused epilogue)
    spmm10<<<spmm10_blocks, blk, 0, stream>>>(rowptr, edges, sup4, z, W5, sup5, N);

    // ---- Layer 5b: out = spmm(sup5) raw
    spmm10<<<spmm10_blocks, blk, 0, stream>>>(rowptr, edges, sup5, nullptr, nullptr, out, N);
}

// Round 14
// 1200.108 us; speedup vs baseline: 1.1779x; 1.0386x over previous
//
#include <hip/hip_runtime.h>
#include <hip/hip_bf16.h>

// GNN: 5-layer GCN on MI355X. Round 14: T14 (issue-early/use-late) tra3 prefetch in
// gemm3_w4. r13 left gemm3_w4 at 241us: K-loop (MFMA 47us) then a serial tail that
// loads the 400MB tra3 tile at the epilogue (latency+BW exposed, 2 blocks/CU can't
// hide it). Now the 8 float4 tra3 loads issue into registers BEFORE the K-loop
// (the "memory"-clobbered vmcnt asm pins them early); epilogue-B is pure cvt+store.
// __launch_bounds__(512,4) pins VGPR<=128 so occupancy stays 2 blocks/CU.
// Everything else unchanged from r13 (D-sliced group-per-row SpMM, counted-vmcnt
// K-loop, XOR swizzle, mix-through-W4, LDS partial combine, CSR counting sort).

#define SCAN_CHUNK 512
#define BM 128
#define BN 128
#define BK 64
#define NSLICE 8       // 512 cols / 64

typedef __attribute__((ext_vector_type(4))) float f32x4;
typedef __attribute__((ext_vector_type(8))) __bf16 bf16x8;
typedef __attribute__((ext_vector_type(8))) short s16x8;

__device__ __forceinline__ bf16x8 as_bf(s16x8 v) { union { s16x8 s; bf16x8 b; } u; u.s = v; return u.b; }
__device__ __forceinline__ ushort f2bf(float f) {
    uint u = __float_as_uint(f);
    return (ushort)((u + 0x7FFFu + ((u >> 16) & 1u)) >> 16);   // RNE
}
__device__ __forceinline__ float bf2f(ushort s) { return __uint_as_float(((uint)s) << 16); }

#define GLL16(g, l)                                                                 \
    __builtin_amdgcn_global_load_lds((const __attribute__((address_space(1))) void*)(g), \
                                     (__attribute__((address_space(3))) void*)(l), 16, 0, 0)

#define STAGE_TILE8(k0, base)                                                       \
    _Pragma("unroll")                                                               \
    for (int i = 0; i < 2; ++i) {                                                   \
        int ar = row0 + arow_off + i * 64;                                          \
        if (ar >= M) ar = M - 1;                                                    \
        GLL16(A + (size_t)ar * 512 + (k0) + acol, &lds[(base) + (w * 8 + i * 64) * BK]); \
        GLL16(Bt + (size_t)(col0 + arow_off + i * 64) * 512 + (k0) + acol,          \
              &lds[(base) + 8192 + (w * 8 + i * 64) * BK]);                         \
    }

#define COMPUTE_TILE8(base)                                                         \
    _Pragma("unroll")                                                               \
    for (int s = 0; s < 2; ++s) {                                                   \
        int cswz = (((s * 4 + (l >> 4)) ^ (l & 7)) << 3);                           \
        bf16x8 af[4], bfr[2];                                                       \
        _Pragma("unroll")                                                           \
        for (int m = 0; m < 4; ++m)                                                 \
            af[m] = as_bf(*(const s16x8*)&lds[(base) + (wr + m * 16 + (l & 15)) * BK + cswz]); \
        _Pragma("unroll")                                                           \
        for (int n = 0; n < 2; ++n)                                                 \
            bfr[n] = as_bf(*(const s16x8*)&lds[(base) + 8192 + (wc + n * 16 + (l & 15)) * BK + cswz]); \
        _Pragma("unroll")                                                           \
        for (int m = 0; m < 4; ++m)                                                 \
            _Pragma("unroll")                                                       \
            for (int n = 0; n < 2; ++n)                                             \
                acc[m][n] = __builtin_amdgcn_mfma_f32_16x16x32_bf16(af[m], bfr[n], acc[m][n], 0, 0, 0); \
    }

#define KLOOP_PIPELINED()                                                           \
    STAGE_TILE8(0, 0);                                                              \
    int base = 0;                                                                   \
    _Pragma("unroll 1")                                                             \
    for (int t = 0; t < 8; ++t) {                                                   \
        if (t < 7) {                                                                \
            STAGE_TILE8((t + 1) * BK, base ^ 16384);                                \
            asm volatile("s_waitcnt vmcnt(4)" ::: "memory");                        \
        } else {                                                                    \
            asm volatile("s_waitcnt vmcnt(0)" ::: "memory");                        \
        }                                                                           \
        __builtin_amdgcn_s_barrier();                                               \
        __builtin_amdgcn_sched_barrier(0);                                          \
        COMPUTE_TILE8(base);                                                        \
        __builtin_amdgcn_sched_barrier(0);                                          \
        __builtin_amdgcn_s_barrier();                                               \
        base ^= 16384;                                                              \
    }

// ---------------- support GEMM: C[M,512]bf16 = A[M,512]bf16 @ Bt[512,512]bf16^T ------
__global__ __launch_bounds__(512) void gemm_sup(const ushort* __restrict__ A,
                                                const ushort* __restrict__ Bt,
                                                ushort* __restrict__ C, int M) {
    __shared__ ushort lds[32768];
    int tid = threadIdx.x;
    int w = tid >> 6, l = tid & 63;
    int row0 = blockIdx.y * BM, col0 = blockIdx.x * BN;
    int wr = (w >> 2) * 64, wc = (w & 3) * 32;
    f32x4 acc[4][2] = {};
    int arow_off = w * 8 + (l >> 3);
    int acol = (((l & 7) ^ (l >> 3)) << 3);

    KLOOP_PIPELINED();

    int crow = (l >> 4) * 4, ccol = l & 15;
#pragma unroll
    for (int m = 0; m < 4; ++m)
#pragma unroll
        for (int n = 0; n < 2; ++n) {
            int gc = col0 + wc + n * 16 + ccol;
#pragma unroll
            for (int r = 0; r < 4; ++r) {
                int gr = row0 + wr + m * 16 + crow + r;
                if (gr < M) C[(size_t)gr * 512 + gc] = f2bf(acc[m][n][r]);
            }
        }
}

// ---------------- fused layer-3: partial = (relu(g@W3) + tra3) @ (0.5*W4) ------------
__global__ __launch_bounds__(512, 4) void gemm3_w4(const ushort* __restrict__ A,
                                                   const ushort* __restrict__ Bt,
                                                   const float* __restrict__ T,
                                                   const float* __restrict__ W4,
                                                   float* __restrict__ sup4p, int M) {
    __shared__ ushort lds[32768];
    int tid = threadIdx.x;
    int w = tid >> 6, l = tid & 63;
    int row0 = blockIdx.y * BM, col0 = blockIdx.x * BN;
    int wr = (w >> 2) * 64, wc = (w & 3) * 32;
    int crow = (l >> 4) * 4, ccol = l & 15;

    bf16x8 w4f;
    {
        s16x8 tmp;
#pragma unroll
        for (int kk = 0; kk < 8; ++kk) {
            int gk = col0 + (w & 3) * 32 + ((l >> 4) << 3) + kk;
            float v = (ccol < 10 && gk < 2000) ? 0.5f * W4[(size_t)gk * 10 + ccol] : 0.f;
            tmp[kk] = (short)f2bf(v);
        }
        w4f = as_bf(tmp);
    }

    // ---- T14: issue tra3 tile loads NOW (used in epilogue B) -> overlap the K-loop.
    // Statically indexed (rule #20); the "memory"-clobbered vmcnt asm pins issue-early.
    float4 tpre[8];
    {
        int r_off = tid >> 5;
        int c4 = (tid & 31) * 4;
#pragma unroll
        for (int p = 0; p < 8; ++p) {
            int rl = p * 16 + r_off;
            int gr = row0 + rl;
            int gcb = col0 + c4;
            if (gr < M && gcb + 3 < 2000)
                tpre[p] = *(const float4*)(T + (size_t)gr * 2000 + gcb);
            else
                tpre[p] = make_float4(0.f, 0.f, 0.f, 0.f);
        }
    }

    f32x4 acc[4][2] = {};
    int arow_off = w * 8 + (l >> 3);
    int acol = (((l & 7) ^ (l >> 3)) << 3);

    KLOOP_PIPELINED();

    ushort* actS = lds;

    __syncthreads();
#pragma unroll
    for (int m = 0; m < 4; ++m)
#pragma unroll
        for (int n = 0; n < 2; ++n) {
            int cl = wc + n * 16 + ccol;
            int cch = cl >> 3, clo = cl & 7;
#pragma unroll
            for (int r = 0; r < 4; ++r) {
                int rl = wr + m * 16 + crow + r;
                actS[rl * 128 + (((cch ^ (rl & 7)) << 3) | clo)] = f2bf(fmaxf(acc[m][n][r], 0.f));
            }
        }
    __syncthreads();

    f32x4 acc2[4] = {};
    {
        int chunk = (w & 3) * 4 + (l >> 4);
#pragma unroll
        for (int m = 0; m < 4; ++m) {
            int row = wr + m * 16 + ccol;
            bf16x8 af = as_bf(*(const s16x8*)&actS[row * 128 + ((chunk ^ (row & 7)) << 3)]);
            acc2[m] = __builtin_amdgcn_mfma_f32_16x16x32_bf16(af, w4f, acc2[m], 0, 0, 0);
        }
    }
    __syncthreads();

    // ---- epilogue B: tra3 tile (prefetched in tpre) -> actS, pure cvt+store
    {
        int r_off = tid >> 5;
        int chunk = (tid & 31) >> 1;
        int lo = (tid & 1) * 4;
#pragma unroll
        for (int p = 0; p < 8; ++p) {
            int rl = p * 16 + r_off;
            float4 tv = tpre[p];
            ushort4 h = { f2bf(tv.x), f2bf(tv.y), f2bf(tv.z), f2bf(tv.w) };
            *(ushort4*)&actS[rl * 128 + ((chunk ^ (rl & 7)) << 3) + lo] = h;
        }
    }
    __syncthreads();

    {
        int chunk = (w & 3) * 4 + (l >> 4);
#pragma unroll
        for (int m = 0; m < 4; ++m) {
            int row = wr + m * 16 + ccol;
            bf16x8 af = as_bf(*(const s16x8*)&actS[row * 128 + ((chunk ^ (row & 7)) << 3)]);
            acc2[m] = __builtin_amdgcn_mfma_f32_16x16x32_bf16(af, w4f, acc2[m], 0, 0, 0);
        }
    }
    __syncthreads();

    float* redS = (float*)lds;   // [4][128][16]
    {
        int q = w & 3;
#pragma unroll
        for (int m = 0; m < 4; ++m)
#pragma unroll
            for (int r = 0; r < 4; ++r) {
                int row = wr + m * 16 + crow + r;
                redS[(q * 128 + row) * 16 + ccol] = acc2[m][r];
            }
    }
    __syncthreads();
    {
        float* dst = sup4p + (size_t)blockIdx.x * ((size_t)M * 10);
#pragma unroll
        for (int p = 0; p < 4; ++p) {
            int o = p * 512 + tid;
            int row = o >> 4, col = o & 15;
            int gr = row0 + row;
            if (col < 10 && gr < M) {
                float s = redS[(0 * 128 + row) * 16 + col] + redS[(1 * 128 + row) * 16 + col]
                        + redS[(2 * 128 + row) * 16 + col] + redS[(3 * 128 + row) * 16 + col];
                dst[(size_t)gr * 10 + col] = s;
            }
        }
    }
}

// ---------------- sum 16 partial slots -> sup4 ----------------
__global__ __launch_bounds__(256) void sup4_reduce(const float* __restrict__ P,
                                                   float* __restrict__ O, int n) {
    int i = blockIdx.x * 256 + threadIdx.x;
    if (i >= n) return;
    float s = 0.f;
#pragma unroll
    for (int j = 0; j < 16; ++j) s += P[(size_t)j * n + i];
    O[i] = s;
}

// ---------------- conversions ----------------
__global__ __launch_bounds__(256) void cvt4(const float* __restrict__ s,
                                            ushort* __restrict__ d, long n4) {
    long i = (long)blockIdx.x * 256 + threadIdx.x;
    if (i >= n4) return;
    float4 v = ((const float4*)s)[i];
    ushort4 o = { f2bf(v.x), f2bf(v.y), f2bf(v.z), f2bf(v.w) };
    ((ushort4*)d)[i] = o;
}

__global__ __launch_bounds__(256) void cvt_wt(const float* __restrict__ W,
                                              ushort* __restrict__ Wt,
                                              int Ksrc, int Nsrc, int Npad) {
    int i = blockIdx.x * 256 + threadIdx.x;
    if (i >= Npad * 512) return;
    int n = i >> 9, k = i & 511;
    float v = (k < Ksrc && n < Nsrc) ? W[(size_t)k * Nsrc + n] : 0.f;
    Wt[i] = f2bf(v);
}

// ---------------- CSR build: count / scan / fill ----------------
__global__ __launch_bounds__(256) void csr_count(const int* __restrict__ rows,
                                                 int* __restrict__ cnt, int E) {
    int e = blockIdx.x * 256 + threadIdx.x;
    if (e < E) atomicAdd(&cnt[rows[e]], 1);
}

__global__ __launch_bounds__(256) void scan1(const int* __restrict__ cnt,
                                             int* __restrict__ csum, int n) {
    __shared__ int red[256];
    int base = blockIdx.x * SCAN_CHUNK;
    int t = threadIdx.x;
    int s = 0;
    if (base + t < n) s += cnt[base + t];
    if (base + t + 256 < n) s += cnt[base + t + 256];
    red[t] = s;
    __syncthreads();
    for (int off = 128; off; off >>= 1) {
        if (t < off) red[t] += red[t + off];
        __syncthreads();
    }
    if (t == 0) csum[blockIdx.x] = red[0];
}

__global__ void scan2(int* csum, int nch) {
    if (threadIdx.x == 0 && blockIdx.x == 0) {
        int acc = 0;
        for (int i = 0; i < nch; ++i) { int v = csum[i]; csum[i] = acc; acc += v; }
    }
}

__global__ __launch_bounds__(256) void scan3(const int* __restrict__ cnt,
                                             const int* __restrict__ csum,
                                             int* __restrict__ rowptr, int n, int E) {
    __shared__ int sm[SCAN_CHUNK];
    int base = blockIdx.x * SCAN_CHUNK;
    int t = threadIdx.x;
    for (int i = t; i < SCAN_CHUNK; i += 256) sm[i] = (base + i < n) ? cnt[base + i] : 0;
    __syncthreads();
    for (int off = 1; off < SCAN_CHUNK; off <<= 1) {
        int i0 = t, i1 = t + 256;
        int v0 = (i0 >= off) ? sm[i0 - off] : 0;
        int v1 = (i1 >= off) ? sm[i1 - off] : 0;
        __syncthreads();
        sm[i0] += v0;
        sm[i1] += v1;
        __syncthreads();
    }
    int off0 = csum[blockIdx.x];
    for (int i = t; i < SCAN_CHUNK; i += 256)
        if (base + i < n) rowptr[base + i] = off0 + (i ? sm[i - 1] : 0);
    if (blockIdx.x == 0 && t == 0) rowptr[n] = E;
}

__global__ __launch_bounds__(256) void csr_fill(const int* __restrict__ rows,
                                                const int* __restrict__ cols,
                                                const float* __restrict__ vals,
                                                int* __restrict__ cur,
                                                int2* __restrict__ edges, int E) {
    int e = blockIdx.x * 256 + threadIdx.x;
    if (e >= E) return;
    int p = atomicAdd(&cur[rows[e]], 1);
    edges[p] = make_int2(cols[e], __float_as_int(vals[e]));
}

// ---------------- D-sliced SpMM gather, GROUP-PER-ROW ----------------
__global__ __launch_bounds__(256) void spmm_bfs(const int* __restrict__ rowptr,
                                                const int2* __restrict__ edges,
                                                const ushort* __restrict__ S,
                                                const float* __restrict__ T,
                                                ushort* __restrict__ O,
                                                int nrows, int domix) {
    int row = (int)((blockIdx.x * 256 + threadIdx.x) >> 3);
    if (row >= nrows) return;
    int t = threadIdx.x & 7;
    int c0 = blockIdx.y * 64 + t * 8;          // this lane's 8-col sub-slice
    int beg = rowptr[row], end = rowptr[row + 1];
    const ushort* Sc = S + c0;

    float acc[8] = {0.f, 0.f, 0.f, 0.f, 0.f, 0.f, 0.f, 0.f};
    int e = beg;
    for (; e + 3 < end; e += 4) {
        int2 e0 = edges[e], e1 = edges[e + 1], e2 = edges[e + 2], e3 = edges[e + 3];
        float v0 = __int_as_float(e0.y), v1 = __int_as_float(e1.y);
        float v2 = __int_as_float(e2.y), v3 = __int_as_float(e3.y);
        s16x8 a = *(const s16x8*)(Sc + (size_t)e0.x * 512);
        s16x8 b = *(const s16x8*)(Sc + (size_t)e1.x * 512);
        s16x8 c = *(const s16x8*)(Sc + (size_t)e2.x * 512);
        s16x8 d = *(const s16x8*)(Sc + (size_t)e3.x * 512);
#pragma unroll
        for (int j = 0; j < 8; ++j)
            acc[j] += v0 * bf2f((ushort)a[j]) + v1 * bf2f((ushort)b[j])
                    + v2 * bf2f((ushort)c[j]) + v3 * bf2f((ushort)d[j]);
    }
    for (; e < end; ++e) {
        int2 e0 = edges[e];
        float v0 = __int_as_float(e0.y);
        s16x8 a = *(const s16x8*)(Sc + (size_t)e0.x * 512);
#pragma unroll
        for (int j = 0; j < 8; ++j)
            acc[j] += v0 * bf2f((ushort)a[j]);
    }

    float res[8];
    if (domix) {
        float tv[8] = {0.f, 0.f, 0.f, 0.f, 0.f, 0.f, 0.f, 0.f};
        const float* trow = T + (size_t)row * 500;
        if (c0 + 8 <= 500) {
            float4 t0 = *(const float4*)(trow + c0);
            float4 t1 = *(const float4*)(trow + c0 + 4);
            tv[0] = t0.x; tv[1] = t0.y; tv[2] = t0.z; tv[3] = t0.w;
            tv[4] = t1.x; tv[5] = t1.y; tv[6] = t1.z; tv[7] = t1.w;
        } else {
#pragma unroll
            for (int j = 0; j < 8; ++j)
                if (c0 + j < 500) tv[j] = trow[c0 + j];
        }
#pragma unroll
        for (int j = 0; j < 8; ++j)
            res[j] = (c0 + j < 500) ? (0.5f * fmaxf(acc[j], 0.f) + 0.5f * tv[j]) : 0.f;
    } else {
#pragma unroll
        for (int j = 0; j < 8; ++j)
            res[j] = (c0 + j < 500) ? acc[j] : 0.f;
    }
    s16x8 o;
#pragma unroll
    for (int j = 0; j < 8; ++j) o[j] = (short)f2bf(res[j]);
    *(s16x8*)(O + (size_t)row * 512 + c0) = o;
}

// ---------------- SpMM gather, D=10 f32; optional fused mix+@W5 epilogue -------------
__global__ __launch_bounds__(256) void spmm10(const int* __restrict__ rowptr,
                                              const int2* __restrict__ edges,
                                              const float* __restrict__ S,
                                              const float* __restrict__ T,
                                              const float* __restrict__ W5,
                                              float* __restrict__ O, int nrows) {
    int g = (int)((blockIdx.x * 256 + threadIdx.x) >> 4);
    int t = threadIdx.x & 15;
    if (g >= nrows || t >= 10) return;
    int beg = rowptr[g], end = rowptr[g + 1];
    float acc = 0.f;
    for (int e = beg; e < end; ++e) {
        int2 ed = edges[e];
        acc += __int_as_float(ed.y) * S[(size_t)ed.x * 10 + t];
    }
    if (W5) {
        float m = 0.5f * fmaxf(acc, 0.f) + 0.5f * T[(size_t)g * 10 + t];
        float s5 = 0.f;
#pragma unroll
        for (int i = 0; i < 10; ++i)
            s5 += __shfl(m, i, 16) * W5[i * 10 + t];
        O[(size_t)g * 10 + t] = s5;
    } else {
        O[(size_t)g * 10 + t] = acc;
    }
}

extern "C" void kernel_launch(void* const* d_in, const int* in_sizes, int n_in,
                              void* d_out, int out_size, void* d_ws, size_t ws_size,
                              hipStream_t stream) {
    const float* x    = (const float*)d_in[0];
    const int*   ar   = (const int*)d_in[1];
    const int*   ac   = (const int*)d_in[2];
    const float* av   = (const float*)d_in[3];
    const float* tra1 = (const float*)d_in[4];
    const float* tra2 = (const float*)d_in[5];
    const float* tra3 = (const float*)d_in[6];
    const float* z    = (const float*)d_in[7];
    const float* W1   = (const float*)d_in[8];
    const float* W2   = (const float*)d_in[9];
    const float* W3   = (const float*)d_in[10];
    const float* W4   = (const float*)d_in[11];
    const float* W5   = (const float*)d_in[12];

    const int E = in_sizes[1];
    const int N = in_sizes[7] / 10;   // 50000
    const int NCH = (N + SCAN_CHUNK - 1) / SCAN_CHUNK;

    ushort* Abf    = (ushort*)d_ws;                     // [N,512] bf16
    ushort* Sbf    = Abf + (size_t)N * 512;             // [N,512] bf16
    ushort* Wt1    = Sbf + (size_t)N * 512;             // [512,512] bf16
    ushort* Wt2    = Wt1 + 512 * 512;                   // [512,512] bf16
    ushort* Wt3    = Wt2 + 512 * 512;                   // [2048,512] bf16
    float*  sup4   = (float*)(Wt3 + 2048 * 512);        // [N,10] f32
    float*  sup5   = sup4 + (size_t)N * 10;             // [N,10] f32
    float*  sup4p  = sup5 + (size_t)N * 10;             // [16][N*10] f32 partials
    int2*   edges  = (int2*)(sup4p + (size_t)16 * N * 10); // [E]
    int*    rowptr = (int*)(edges + E);                 // [N+1]
    int*    cnt    = rowptr + (N + 1);                  // [N]
    int*    csum   = cnt + N;                           // [NCH]
    float*  out    = (float*)d_out;

    dim3 blk(256);
    dim3 blk8(512);

    // ---- all conversions upfront (independent) ----
    cvt4<<<(int)(((long)N * 512 / 4 + 255) / 256), blk, 0, stream>>>(x, Abf, (long)N * 512 / 4);
    cvt_wt<<<(512 * 512 + 255) / 256, blk, 0, stream>>>(W1, Wt1, 512, 500, 512);
    cvt_wt<<<(512 * 512 + 255) / 256, blk, 0, stream>>>(W2, Wt2, 500, 500, 512);
    cvt_wt<<<(2048 * 512 + 255) / 256, blk, 0, stream>>>(W3, Wt3, 500, 2000, 2048);

    // ---- CSR build ----
    hipMemsetAsync(cnt, 0, (size_t)N * sizeof(int), stream);
    csr_count<<<(E + 255) / 256, blk, 0, stream>>>(ar, cnt, E);
    scan1<<<NCH, blk, 0, stream>>>(cnt, csum, N);
    scan2<<<1, 64, 0, stream>>>(csum, NCH);
    scan3<<<NCH, blk, 0, stream>>>(cnt, csum, rowptr, N, E);
    hipMemcpyAsync(cnt, rowptr, (size_t)N * sizeof(int), hipMemcpyDeviceToDevice, stream);
    csr_fill<<<(E + 255) / 256, blk, 0, stream>>>(ar, ac, av, cnt, edges, E);

    dim3 spmm_grid((N * 8 + 255) / 256, NSLICE);
    const int spmm10_blocks = (N * 16 + 255) / 256;

    // ---- Layer 1: Sbf = Abf@W1t; Abf = mix(spmm(Sbf), tra1)
    {
        dim3 g(4, (N + BM - 1) / BM);
        gemm_sup<<<g, blk8, 0, stream>>>(Abf, Wt1, Sbf, N);
    }
    spmm_bfs<<<spmm_grid, blk, 0, stream>>>(rowptr, edges, Sbf, tra1, Abf, N, 1);

    // ---- Layer 2: Sbf = Abf@W2t; Abf(m2) = mix(spmm(Sbf), tra2)
    {
        dim3 g(4, (N + BM - 1) / BM);
        gemm_sup<<<g, blk8, 0, stream>>>(Abf, Wt2, Sbf, N);
    }
    spmm_bfs<<<spmm_grid, blk, 0, stream>>>(rowptr, edges, Sbf, tra2, Abf, N, 1);

    // ---- Layer 3 (spmm-first, fused): Sbf(g) = spmm(m2) raw;
    //      sup4p[16 slots] = (relu(g@W3)+tra3)@(0.5*W4) partials; sup4 = sum
    spmm_bfs<<<spmm_grid, blk, 0, stream>>>(rowptr, edges, Abf, nullptr, Sbf, N, 0);
    {
        dim3 g(16, (N + BM - 1) / BM);
        gemm3_w4<<<g, blk8, 0, stream>>>(Sbf, Wt3, tra3, W4, sup4p, N);
    }
    sup4_reduce<<<(N * 10 + 255) / 256, blk, 0, stream>>>(sup4p, sup4, N * 10);

    // ---- Layer 4+5a: sup5 = (mix(spmm(sup4), z)) @ W5  (fused epilogue)
    spmm10<<<spmm10_blocks, blk, 0, stream>>>(rowptr, edges, sup4, z, W5, sup5, N);

    // ---- Layer 5b: out = spmm(sup5) raw
    spmm10<<<spmm10_blocks, blk, 0, stream>>>(rowptr, edges, sup5, nullptr, nullptr, out, N);
}

// Round 15
// 1162.961 us; speedup vs baseline: 1.2156x; 1.0319x over previous
//
#include <hip/hip_runtime.h>
#include <hip/hip_bf16.h>

// GNN: 5-layer GCN on MI355X. Round 15: 4-byte packed edges.
// r14 budget: 3x spmm_bfs ~45% of 1200us; FETCH 558MB = 400MB XCD-replication floor
// + 100MB tra + ~102MB edge re-reads (12.8MB x 8 passes). col < 65536 -> pack
// (bf16(val)<<16)|col into one uint: edge array 12.8->6.4MB, halves edge traffic on
// every spmm pass + csr_fill writes + spmm10 reads. Value->bf16 is the same precision
// grade as the rest of the pipeline.
// Unchanged: D-sliced group-per-row SpMM (r13), T14 tra3 prefetch (r14),
// counted-vmcnt MFMA K-loop + XOR swizzle (r10/r6), mix-through-W4 (r8),
// LDS partial combine (r10), CSR counting sort.

#define SCAN_CHUNK 512
#define BM 128
#define BN 128
#define BK 64
#define NSLICE 8       // 512 cols / 64

typedef __attribute__((ext_vector_type(4))) float f32x4;
typedef __attribute__((ext_vector_type(8))) __bf16 bf16x8;
typedef __attribute__((ext_vector_type(8))) short s16x8;

__device__ __forceinline__ bf16x8 as_bf(s16x8 v) { union { s16x8 s; bf16x8 b; } u; u.s = v; return u.b; }
__device__ __forceinline__ ushort f2bf(float f) {
    uint u = __float_as_uint(f);
    return (ushort)((u + 0x7FFFu + ((u >> 16) & 1u)) >> 16);   // RNE
}
__device__ __forceinline__ float bf2f(ushort s) { return __uint_as_float(((uint)s) << 16); }

#define GLL16(g, l)                                                                 \
    __builtin_amdgcn_global_load_lds((const __attribute__((address_space(1))) void*)(g), \
                                     (__attribute__((address_space(3))) void*)(l), 16, 0, 0)

#define STAGE_TILE8(k0, base)                                                       \
    _Pragma("unroll")                                                               \
    for (int i = 0; i < 2; ++i) {                                                   \
        int ar = row0 + arow_off + i * 64;                                          \
        if (ar >= M) ar = M - 1;                                                    \
        GLL16(A + (size_t)ar * 512 + (k0) + acol, &lds[(base) + (w * 8 + i * 64) * BK]); \
        GLL16(Bt + (size_t)(col0 + arow_off + i * 64) * 512 + (k0) + acol,          \
              &lds[(base) + 8192 + (w * 8 + i * 64) * BK]);                         \
    }

#define COMPUTE_TILE8(base)                                                         \
    _Pragma("unroll")                                                               \
    for (int s = 0; s < 2; ++s) {                                                   \
        int cswz = (((s * 4 + (l >> 4)) ^ (l & 7)) << 3);                           \
        bf16x8 af[4], bfr[2];                                                       \
        _Pragma("unroll")                                                           \
        for (int m = 0; m < 4; ++m)                                                 \
            af[m] = as_bf(*(const s16x8*)&lds[(base) + (wr + m * 16 + (l & 15)) * BK + cswz]); \
        _Pragma("unroll")                                                           \
        for (int n = 0; n < 2; ++n)                                                 \
            bfr[n] = as_bf(*(const s16x8*)&lds[(base) + 8192 + (wc + n * 16 + (l & 15)) * BK + cswz]); \
        _Pragma("unroll")                                                           \
        for (int m = 0; m < 4; ++m)                                                 \
            _Pragma("unroll")                                                       \
            for (int n = 0; n < 2; ++n)                                             \
                acc[m][n] = __builtin_amdgcn_mfma_f32_16x16x32_bf16(af[m], bfr[n], acc[m][n], 0, 0, 0); \
    }

#define KLOOP_PIPELINED()                                                           \
    STAGE_TILE8(0, 0);                                                              \
    int base = 0;                                                                   \
    _Pragma("unroll 1")                                                             \
    for (int t = 0; t < 8; ++t) {                                                   \
        if (t < 7) {                                                                \
            STAGE_TILE8((t + 1) * BK, base ^ 16384);                                \
            asm volatile("s_waitcnt vmcnt(4)" ::: "memory");                        \
        } else {                                                                    \
            asm volatile("s_waitcnt vmcnt(0)" ::: "memory");                        \
        }                                                                           \
        __builtin_amdgcn_s_barrier();                                               \
        __builtin_amdgcn_sched_barrier(0);                                          \
        COMPUTE_TILE8(base);                                                        \
        __builtin_amdgcn_sched_barrier(0);                                          \
        __builtin_amdgcn_s_barrier();                                               \
        base ^= 16384;                                                              \
    }

// ---------------- support GEMM: C[M,512]bf16 = A[M,512]bf16 @ Bt[512,512]bf16^T ------
__global__ __launch_bounds__(512) void gemm_sup(const ushort* __restrict__ A,
                                                const ushort* __restrict__ Bt,
                                                ushort* __restrict__ C, int M) {
    __shared__ ushort lds[32768];
    int tid = threadIdx.x;
    int w = tid >> 6, l = tid & 63;
    int row0 = blockIdx.y * BM, col0 = blockIdx.x * BN;
    int wr = (w >> 2) * 64, wc = (w & 3) * 32;
    f32x4 acc[4][2] = {};
    int arow_off = w * 8 + (l >> 3);
    int acol = (((l & 7) ^ (l >> 3)) << 3);

    KLOOP_PIPELINED();

    int crow = (l >> 4) * 4, ccol = l & 15;
#pragma unroll
    for (int m = 0; m < 4; ++m)
#pragma unroll
        for (int n = 0; n < 2; ++n) {
            int gc = col0 + wc + n * 16 + ccol;
#pragma unroll
            for (int r = 0; r < 4; ++r) {
                int gr = row0 + wr + m * 16 + crow + r;
                if (gr < M) C[(size_t)gr * 512 + gc] = f2bf(acc[m][n][r]);
            }
        }
}

// ---------------- fused layer-3: partial = (relu(g@W3) + tra3) @ (0.5*W4) ------------
__global__ __launch_bounds__(512, 4) void gemm3_w4(const ushort* __restrict__ A,
                                                   const ushort* __restrict__ Bt,
                                                   const float* __restrict__ T,
                                                   const float* __restrict__ W4,
                                                   float* __restrict__ sup4p, int M) {
    __shared__ ushort lds[32768];
    int tid = threadIdx.x;
    int w = tid >> 6, l = tid & 63;
    int row0 = blockIdx.y * BM, col0 = blockIdx.x * BN;
    int wr = (w >> 2) * 64, wc = (w & 3) * 32;
    int crow = (l >> 4) * 4, ccol = l & 15;

    bf16x8 w4f;
    {
        s16x8 tmp;
#pragma unroll
        for (int kk = 0; kk < 8; ++kk) {
            int gk = col0 + (w & 3) * 32 + ((l >> 4) << 3) + kk;
            float v = (ccol < 10 && gk < 2000) ? 0.5f * W4[(size_t)gk * 10 + ccol] : 0.f;
            tmp[kk] = (short)f2bf(v);
        }
        w4f = as_bf(tmp);
    }

    // T14: issue tra3 tile loads before the K-loop (used in epilogue B)
    float4 tpre[8];
    {
        int r_off = tid >> 5;
        int c4 = (tid & 31) * 4;
#pragma unroll
        for (int p = 0; p < 8; ++p) {
            int rl = p * 16 + r_off;
            int gr = row0 + rl;
            int gcb = col0 + c4;
            if (gr < M && gcb + 3 < 2000)
                tpre[p] = *(const float4*)(T + (size_t)gr * 2000 + gcb);
            else
                tpre[p] = make_float4(0.f, 0.f, 0.f, 0.f);
        }
    }

    f32x4 acc[4][2] = {};
    int arow_off = w * 8 + (l >> 3);
    int acol = (((l & 7) ^ (l >> 3)) << 3);

    KLOOP_PIPELINED();

    ushort* actS = lds;

    __syncthreads();
#pragma unroll
    for (int m = 0; m < 4; ++m)
#pragma unroll
        for (int n = 0; n < 2; ++n) {
            int cl = wc + n * 16 + ccol;
            int cch = cl >> 3, clo = cl & 7;
#pragma unroll
            for (int r = 0; r < 4; ++r) {
                int rl = wr + m * 16 + crow + r;
                actS[rl * 128 + (((cch ^ (rl & 7)) << 3) | clo)] = f2bf(fmaxf(acc[m][n][r], 0.f));
            }
        }
    __syncthreads();

    f32x4 acc2[4] = {};
    {
        int chunk = (w & 3) * 4 + (l >> 4);
#pragma unroll
        for (int m = 0; m < 4; ++m) {
            int row = wr + m * 16 + ccol;
            bf16x8 af = as_bf(*(const s16x8*)&actS[row * 128 + ((chunk ^ (row & 7)) << 3)]);
            acc2[m] = __builtin_amdgcn_mfma_f32_16x16x32_bf16(af, w4f, acc2[m], 0, 0, 0);
        }
    }
    __syncthreads();

    // epilogue B: prefetched tra3 tile -> actS (pure cvt+store)
    {
        int r_off = tid >> 5;
        int chunk = (tid & 31) >> 1;
        int lo = (tid & 1) * 4;
#pragma unroll
        for (int p = 0; p < 8; ++p) {
            int rl = p * 16 + r_off;
            float4 tv = tpre[p];
            ushort4 h = { f2bf(tv.x), f2bf(tv.y), f2bf(tv.z), f2bf(tv.w) };
            *(ushort4*)&actS[rl * 128 + ((chunk ^ (rl & 7)) << 3) + lo] = h;
        }
    }
    __syncthreads();

    {
        int chunk = (w & 3) * 4 + (l >> 4);
#pragma unroll
        for (int m = 0; m < 4; ++m) {
            int row = wr + m * 16 + ccol;
            bf16x8 af = as_bf(*(const s16x8*)&actS[row * 128 + ((chunk ^ (row & 7)) << 3)]);
            acc2[m] = __builtin_amdgcn_mfma_f32_16x16x32_bf16(af, w4f, acc2[m], 0, 0, 0);
        }
    }
    __syncthreads();

    float* redS = (float*)lds;   // [4][128][16]
    {
        int q = w & 3;
#pragma unroll
        for (int m = 0; m < 4; ++m)
#pragma unroll
            for (int r = 0; r < 4; ++r) {
                int row = wr + m * 16 + crow + r;
                redS[(q * 128 + row) * 16 + ccol] = acc2[m][r];
            }
    }
    __syncthreads();
    {
        float* dst = sup4p + (size_t)blockIdx.x * ((size_t)M * 10);
#pragma unroll
        for (int p = 0; p < 4; ++p) {
            int o = p * 512 + tid;
            int row = o >> 4, col = o & 15;
            int gr = row0 + row;
            if (col < 10 && gr < M) {
                float s = redS[(0 * 128 + row) * 16 + col] + redS[(1 * 128 + row) * 16 + col]
                        + redS[(2 * 128 + row) * 16 + col] + redS[(3 * 128 + row) * 16 + col];
                dst[(size_t)gr * 10 + col] = s;
            }
        }
    }
}

// ---------------- sum 16 partial slots -> sup4 ----------------
__global__ __launch_bounds__(256) void sup4_reduce(const float* __restrict__ P,
                                                   float* __restrict__ O, int n) {
    int i = blockIdx.x * 256 + threadIdx.x;
    if (i >= n) return;
    float s = 0.f;
#pragma unroll
    for (int j = 0; j < 16; ++j) s += P[(size_t)j * n + i];
    O[i] = s;
}

// ---------------- conversions ----------------
__global__ __launch_bounds__(256) void cvt4(const float* __restrict__ s,
                                            ushort* __restrict__ d, long n4) {
    long i = (long)blockIdx.x * 256 + threadIdx.x;
    if (i >= n4) return;
    float4 v = ((const float4*)s)[i];
    ushort4 o = { f2bf(v.x), f2bf(v.y), f2bf(v.z), f2bf(v.w) };
    ((ushort4*)d)[i] = o;
}

__global__ __launch_bounds__(256) void cvt_wt(const float* __restrict__ W,
                                              ushort* __restrict__ Wt,
                                              int Ksrc, int Nsrc, int Npad) {
    int i = blockIdx.x * 256 + threadIdx.x;
    if (i >= Npad * 512) return;
    int n = i >> 9, k = i & 511;
    float v = (k < Ksrc && n < Nsrc) ? W[(size_t)k * Nsrc + n] : 0.f;
    Wt[i] = f2bf(v);
}

// ---------------- CSR build: count / scan / fill (packed 4B edges) ----------------
__global__ __launch_bounds__(256) void csr_count(const int* __restrict__ rows,
                                                 int* __restrict__ cnt, int E) {
    int e = blockIdx.x * 256 + threadIdx.x;
    if (e < E) atomicAdd(&cnt[rows[e]], 1);
}

__global__ __launch_bounds__(256) void scan1(const int* __restrict__ cnt,
                                             int* __restrict__ csum, int n) {
    __shared__ int red[256];
    int base = blockIdx.x * SCAN_CHUNK;
    int t = threadIdx.x;
    int s = 0;
    if (base + t < n) s += cnt[base + t];
    if (base + t + 256 < n) s += cnt[base + t + 256];
    red[t] = s;
    __syncthreads();
    for (int off = 128; off; off >>= 1) {
        if (t < off) red[t] += red[t + off];
        __syncthreads();
    }
    if (t == 0) csum[blockIdx.x] = red[0];
}

__global__ void scan2(int* csum, int nch) {
    if (threadIdx.x == 0 && blockIdx.x == 0) {
        int acc = 0;
        for (int i = 0; i < nch; ++i) { int v = csum[i]; csum[i] = acc; acc += v; }
    }
}

__global__ __launch_bounds__(256) void scan3(const int* __restrict__ cnt,
                                             const int* __restrict__ csum,
                                             int* __restrict__ rowptr, int n, int E) {
    __shared__ int sm[SCAN_CHUNK];
    int base = blockIdx.x * SCAN_CHUNK;
    int t = threadIdx.x;
    for (int i = t; i < SCAN_CHUNK; i += 256) sm[i] = (base + i < n) ? cnt[base + i] : 0;
    __syncthreads();
    for (int off = 1; off < SCAN_CHUNK; off <<= 1) {
        int i0 = t, i1 = t + 256;
        int v0 = (i0 >= off) ? sm[i0 - off] : 0;
        int v1 = (i1 >= off) ? sm[i1 - off] : 0;
        __syncthreads();
        sm[i0] += v0;
        sm[i1] += v1;
        __syncthreads();
    }
    int off0 = csum[blockIdx.x];
    for (int i = t; i < SCAN_CHUNK; i += 256)
        if (base + i < n) rowptr[base + i] = off0 + (i ? sm[i - 1] : 0);
    if (blockIdx.x == 0 && t == 0) rowptr[n] = E;
}

// edge packed as (bf16(val) << 16) | col   [col < 65536]
__global__ __launch_bounds__(256) void csr_fill(const int* __restrict__ rows,
                                                const int* __restrict__ cols,
                                                const float* __restrict__ vals,
                                                int* __restrict__ cur,
                                                uint* __restrict__ edges, int E) {
    int e = blockIdx.x * 256 + threadIdx.x;
    if (e >= E) return;
    int p = atomicAdd(&cur[rows[e]], 1);
    edges[p] = ((uint)f2bf(vals[e]) << 16) | (uint)cols[e];
}

// ---------------- D-sliced SpMM gather, GROUP-PER-ROW, packed edges ----------------
__global__ __launch_bounds__(256) void spmm_bfs(const int* __restrict__ rowptr,
                                                const uint* __restrict__ edges,
                                                const ushort* __restrict__ S,
                                                const float* __restrict__ T,
                                                ushort* __restrict__ O,
                                                int nrows, int domix) {
    int row = (int)((blockIdx.x * 256 + threadIdx.x) >> 3);
    if (row >= nrows) return;
    int t = threadIdx.x & 7;
    int c0 = blockIdx.y * 64 + t * 8;
    int beg = rowptr[row], end = rowptr[row + 1];
    const ushort* Sc = S + c0;

    float acc[8] = {0.f, 0.f, 0.f, 0.f, 0.f, 0.f, 0.f, 0.f};
    int e = beg;
    for (; e + 3 < end; e += 4) {
        uint e0 = edges[e], e1 = edges[e + 1], e2 = edges[e + 2], e3 = edges[e + 3];
        float v0 = bf2f((ushort)(e0 >> 16)), v1 = bf2f((ushort)(e1 >> 16));
        float v2 = bf2f((ushort)(e2 >> 16)), v3 = bf2f((ushort)(e3 >> 16));
        s16x8 a = *(const s16x8*)(Sc + (size_t)(e0 & 0xFFFFu) * 512);
        s16x8 b = *(const s16x8*)(Sc + (size_t)(e1 & 0xFFFFu) * 512);
        s16x8 c = *(const s16x8*)(Sc + (size_t)(e2 & 0xFFFFu) * 512);
        s16x8 d = *(const s16x8*)(Sc + (size_t)(e3 & 0xFFFFu) * 512);
#pragma unroll
        for (int j = 0; j < 8; ++j)
            acc[j] += v0 * bf2f((ushort)a[j]) + v1 * bf2f((ushort)b[j])
                    + v2 * bf2f((ushort)c[j]) + v3 * bf2f((ushort)d[j]);
    }
    for (; e < end; ++e) {
        uint e0 = edges[e];
        float v0 = bf2f((ushort)(e0 >> 16));
        s16x8 a = *(const s16x8*)(Sc + (size_t)(e0 & 0xFFFFu) * 512);
#pragma unroll
        for (int j = 0; j < 8; ++j)
            acc[j] += v0 * bf2f((ushort)a[j]);
    }

    float res[8];
    if (domix) {
        float tv[8] = {0.f, 0.f, 0.f, 0.f, 0.f, 0.f, 0.f, 0.f};
        const float* trow = T + (size_t)row * 500;
        if (c0 + 8 <= 500) {
            float4 t0 = *(const float4*)(trow + c0);
            float4 t1 = *(const float4*)(trow + c0 + 4);
            tv[0] = t0.x; tv[1] = t0.y; tv[2] = t0.z; tv[3] = t0.w;
            tv[4] = t1.x; tv[5] = t1.y; tv[6] = t1.z; tv[7] = t1.w;
        } else {
#pragma unroll
            for (int j = 0; j < 8; ++j)
                if (c0 + j < 500) tv[j] = trow[c0 + j];
        }
#pragma unroll
        for (int j = 0; j < 8; ++j)
            res[j] = (c0 + j < 500) ? (0.5f * fmaxf(acc[j], 0.f) + 0.5f * tv[j]) : 0.f;
    } else {
#pragma unroll
        for (int j = 0; j < 8; ++j)
            res[j] = (c0 + j < 500) ? acc[j] : 0.f;
    }
    s16x8 o;
#pragma unroll
    for (int j = 0; j < 8; ++j) o[j] = (short)f2bf(res[j]);
    *(s16x8*)(O + (size_t)row * 512 + c0) = o;
}

// ---------------- SpMM gather, D=10 f32, packed edges; optional mix+@W5 epilogue -----
__global__ __launch_bounds__(256) void spmm10(const int* __restrict__ rowptr,
                                              const uint* __restrict__ edges,
                                              const float* __restrict__ S,
                                              const float* __restrict__ T,
                                              const float* __restrict__ W5,
                                              float* __restrict__ O, int nrows) {
    int g = (int)((blockIdx.x * 256 + threadIdx.x) >> 4);
    int t = threadIdx.x & 15;
    if (g >= nrows || t >= 10) return;
    int beg = rowptr[g], end = rowptr[g + 1];
    float acc = 0.f;
    for (int e = beg; e < end; ++e) {
        uint ed = edges[e];
        acc += bf2f((ushort)(ed >> 16)) * S[(size_t)(ed & 0xFFFFu) * 10 + t];
    }
    if (W5) {
        float m = 0.5f * fmaxf(acc, 0.f) + 0.5f * T[(size_t)g * 10 + t];
        float s5 = 0.f;
#pragma unroll
        for (int i = 0; i < 10; ++i)
            s5 += __shfl(m, i, 16) * W5[i * 10 + t];
        O[(size_t)g * 10 + t] = s5;
    } else {
        O[(size_t)g * 10 + t] = acc;
    }
}

extern "C" void kernel_launch(void* const* d_in, const int* in_sizes, int n_in,
                              void* d_out, int out_size, void* d_ws, size_t ws_size,
                              hipStream_t stream) {
    const float* x    = (const float*)d_in[0];
    const int*   ar   = (const int*)d_in[1];
    const int*   ac   = (const int*)d_in[2];
    const float* av   = (const float*)d_in[3];
    const float* tra1 = (const float*)d_in[4];
    const float* tra2 = (const float*)d_in[5];
    const float* tra3 = (const float*)d_in[6];
    const float* z    = (const float*)d_in[7];
    const float* W1   = (const float*)d_in[8];
    const float* W2   = (const float*)d_in[9];
    const float* W3   = (const float*)d_in[10];
    const float* W4   = (const float*)d_in[11];
    const float* W5   = (const float*)d_in[12];

    const int E = in_sizes[1];
    const int N = in_sizes[7] / 10;   // 50000 (< 65536 -> u16 col packing valid)
    const int NCH = (N + SCAN_CHUNK - 1) / SCAN_CHUNK;

    ushort* Abf    = (ushort*)d_ws;                     // [N,512] bf16
    ushort* Sbf    = Abf + (size_t)N * 512;             // [N,512] bf16
    ushort* Wt1    = Sbf + (size_t)N * 512;             // [512,512] bf16
    ushort* Wt2    = Wt1 + 512 * 512;                   // [512,512] bf16
    ushort* Wt3    = Wt2 + 512 * 512;                   // [2048,512] bf16
    float*  sup4   = (float*)(Wt3 + 2048 * 512);        // [N,10] f32
    float*  sup5   = sup4 + (size_t)N * 10;             // [N,10] f32
    float*  sup4p  = sup5 + (size_t)N * 10;             // [16][N*10] f32 partials
    uint*   edges  = (uint*)(sup4p + (size_t)16 * N * 10); // [E] packed 4B
    int*    rowptr = (int*)(edges + E);                 // [N+1]
    int*    cnt    = rowptr + (N + 1);                  // [N]
    int*    csum   = cnt + N;                           // [NCH]
    float*  out    = (float*)d_out;

    dim3 blk(256);
    dim3 blk8(512);

    // ---- all conversions upfront (independent) ----
    cvt4<<<(int)(((long)N * 512 / 4 + 255) / 256), blk, 0, stream>>>(x, Abf, (long)N * 512 / 4);
    cvt_wt<<<(512 * 512 + 255) / 256, blk, 0, stream>>>(W1, Wt1, 512, 500, 512);
    cvt_wt<<<(512 * 512 + 255) / 256, blk, 0, stream>>>(W2, Wt2, 500, 500, 512);
    cvt_wt<<<(2048 * 512 + 255) / 256, blk, 0, stream>>>(W3, Wt3, 500, 2000, 2048);

    // ---- CSR build ----
    hipMemsetAsync(cnt, 0, (size_t)N * sizeof(int), stream);
    csr_count<<<(E + 255) / 256, blk, 0, stream>>>(ar, cnt, E);
    scan1<<<NCH, blk, 0, stream>>>(cnt, csum, N);
    scan2<<<1, 64, 0, stream>>>(csum, NCH);
    scan3<<<NCH, blk, 0, stream>>>(cnt, csum, rowptr, N, E);
    hipMemcpyAsync(cnt, rowptr, (size_t)N * sizeof(int), hipMemcpyDeviceToDevice, stream);
    csr_fill<<<(E + 255) / 256, blk, 0, stream>>>(ar, ac, av, cnt, edges, E);

    dim3 spmm_grid((N * 8 + 255) / 256, NSLICE);
    const int spmm10_blocks = (N * 16 + 255) / 256;

    // ---- Layer 1: Sbf = Abf@W1t; Abf = mix(spmm(Sbf), tra1)
    {
        dim3 g(4, (N + BM - 1) / BM);
        gemm_sup<<<g, blk8, 0, stream>>>(Abf, Wt1, Sbf, N);
    }
    spmm_bfs<<<spmm_grid, blk, 0, stream>>>(rowptr, edges, Sbf, tra1, Abf, N, 1);

    // ---- Layer 2: Sbf = Abf@W2t; Abf(m2) = mix(spmm(Sbf), tra2)
    {
        dim3 g(4, (N + BM - 1) / BM);
        gemm_sup<<<g, blk8, 0, stream>>>(Abf, Wt2, Sbf, N);
    }
    spmm_bfs<<<spmm_grid, blk, 0, stream>>>(rowptr, edges, Sbf, tra2, Abf, N, 1);

    // ---- Layer 3 (spmm-first, fused): Sbf(g) = spmm(m2) raw;
    //      sup4p[16 slots] = (relu(g@W3)+tra3)@(0.5*W4) partials; sup4 = sum
    spmm_bfs<<<spmm_grid, blk, 0, stream>>>(rowptr, edges, Abf, nullptr, Sbf, N, 0);
    {
        dim3 g(16, (N + BM - 1) / BM);
        gemm3_w4<<<g, blk8, 0, stream>>>(Sbf, Wt3, tra3, W4, sup4p, N);
    }
    sup4_reduce<<<(N * 10 + 255) / 256, blk, 0, stream>>>(sup4p, sup4, N * 10);

    // ---- Layer 4+5a: sup5 = (mix(spmm(sup4), z)) @ W5  (fused epilogue)
    spmm10<<<spmm10_blocks, blk, 0, stream>>>(rowptr, edges, sup4, z, W5, sup5, N);

    // ---- Layer 5b: out = spmm(sup5) raw
    spmm10<<<spmm10_blocks, blk, 0, stream>>>(rowptr, edges, sup5, nullptr, nullptr, out, N);
}

// Round 16
// 1099.764 us; speedup vs baseline: 1.2854x; 1.0575x over previous
//
#include <hip/hip_runtime.h>
#include <hip/hip_bf16.h>

// GNN: 5-layer GCN on MI355X. Round 16:
// - spmm_bfs: 8-edge unroll (8 concurrent 128B line-gathers per group; r4's unsliced
//   kernel proved 3.77 TB/s on this path, current sliced runs 3.0 -> latency-limited).
// - cvt_wt x3 fused into one kernel (Wt1/Wt2/Wt3 contiguous); scan3 writes cur[] too
//   (drops the cnt<-rowptr memcpy). 3 fewer dispatches.
// Unchanged: packed 4B edges (r15), T14 tra3 prefetch (r14), D-sliced group-per-row
// SpMM (r13), counted-vmcnt MFMA K-loop + XOR swizzle (r10/r6), mix-through-W4 (r8),
// LDS partial combine (r10).

#define SCAN_CHUNK 512
#define BM 128
#define BN 128
#define BK 64
#define NSLICE 8       // 512 cols / 64

typedef __attribute__((ext_vector_type(4))) float f32x4;
typedef __attribute__((ext_vector_type(8))) __bf16 bf16x8;
typedef __attribute__((ext_vector_type(8))) short s16x8;

__device__ __forceinline__ bf16x8 as_bf(s16x8 v) { union { s16x8 s; bf16x8 b; } u; u.s = v; return u.b; }
__device__ __forceinline__ ushort f2bf(float f) {
    uint u = __float_as_uint(f);
    return (ushort)((u + 0x7FFFu + ((u >> 16) & 1u)) >> 16);   // RNE
}
__device__ __forceinline__ float bf2f(ushort s) { return __uint_as_float(((uint)s) << 16); }

#define GLL16(g, l)                                                                 \
    __builtin_amdgcn_global_load_lds((const __attribute__((address_space(1))) void*)(g), \
                                     (__attribute__((address_space(3))) void*)(l), 16, 0, 0)

#define STAGE_TILE8(k0, base)                                                       \
    _Pragma("unroll")                                                               \
    for (int i = 0; i < 2; ++i) {                                                   \
        int ar = row0 + arow_off + i * 64;                                          \
        if (ar >= M) ar = M - 1;                                                    \
        GLL16(A + (size_t)ar * 512 + (k0) + acol, &lds[(base) + (w * 8 + i * 64) * BK]); \
        GLL16(Bt + (size_t)(col0 + arow_off + i * 64) * 512 + (k0) + acol,          \
              &lds[(base) + 8192 + (w * 8 + i * 64) * BK]);                         \
    }

#define COMPUTE_TILE8(base)                                                         \
    _Pragma("unroll")                                                               \
    for (int s = 0; s < 2; ++s) {                                                   \
        int cswz = (((s * 4 + (l >> 4)) ^ (l & 7)) << 3);                           \
        bf16x8 af[4], bfr[2];                                                       \
        _Pragma("unroll")                                                           \
        for (int m = 0; m < 4; ++m)                                                 \
            af[m] = as_bf(*(const s16x8*)&lds[(base) + (wr + m * 16 + (l & 15)) * BK + cswz]); \
        _Pragma("unroll")                                                           \
        for (int n = 0; n < 2; ++n)                                                 \
            bfr[n] = as_bf(*(const s16x8*)&lds[(base) + 8192 + (wc + n * 16 + (l & 15)) * BK + cswz]); \
        _Pragma("unroll")                                                           \
        for (int m = 0; m < 4; ++m)                                                 \
            _Pragma("unroll")                                                       \
            for (int n = 0; n < 2; ++n)                                             \
                acc[m][n] = __builtin_amdgcn_mfma_f32_16x16x32_bf16(af[m], bfr[n], acc[m][n], 0, 0, 0); \
    }

#define KLOOP_PIPELINED()                                                           \
    STAGE_TILE8(0, 0);                                                              \
    int base = 0;                                                                   \
    _Pragma("unroll 1")                                                             \
    for (int t = 0; t < 8; ++t) {                                                   \
        if (t < 7) {                                                                \
            STAGE_TILE8((t + 1) * BK, base ^ 16384);                                \
            asm volatile("s_waitcnt vmcnt(4)" ::: "memory");                        \
        } else {                                                                    \
            asm volatile("s_waitcnt vmcnt(0)" ::: "memory");                        \
        }                                                                           \
        __builtin_amdgcn_s_barrier();                                               \
        __builtin_amdgcn_sched_barrier(0);                                          \
        COMPUTE_TILE8(base);                                                        \
        __builtin_amdgcn_sched_barrier(0);                                          \
        __builtin_amdgcn_s_barrier();                                               \
        base ^= 16384;                                                              \
    }

// ---------------- support GEMM: C[M,512]bf16 = A[M,512]bf16 @ Bt[512,512]bf16^T ------
__global__ __launch_bounds__(512) void gemm_sup(const ushort* __restrict__ A,
                                                const ushort* __restrict__ Bt,
                                                ushort* __restrict__ C, int M) {
    __shared__ ushort lds[32768];
    int tid = threadIdx.x;
    int w = tid >> 6, l = tid & 63;
    int row0 = blockIdx.y * BM, col0 = blockIdx.x * BN;
    int wr = (w >> 2) * 64, wc = (w & 3) * 32;
    f32x4 acc[4][2] = {};
    int arow_off = w * 8 + (l >> 3);
    int acol = (((l & 7) ^ (l >> 3)) << 3);

    KLOOP_PIPELINED();

    int crow = (l >> 4) * 4, ccol = l & 15;
#pragma unroll
    for (int m = 0; m < 4; ++m)
#pragma unroll
        for (int n = 0; n < 2; ++n) {
            int gc = col0 + wc + n * 16 + ccol;
#pragma unroll
            for (int r = 0; r < 4; ++r) {
                int gr = row0 + wr + m * 16 + crow + r;
                if (gr < M) C[(size_t)gr * 512 + gc] = f2bf(acc[m][n][r]);
            }
        }
}

// ---------------- fused layer-3: partial = (relu(g@W3) + tra3) @ (0.5*W4) ------------
__global__ __launch_bounds__(512, 4) void gemm3_w4(const ushort* __restrict__ A,
                                                   const ushort* __restrict__ Bt,
                                                   const float* __restrict__ T,
                                                   const float* __restrict__ W4,
                                                   float* __restrict__ sup4p, int M) {
    __shared__ ushort lds[32768];
    int tid = threadIdx.x;
    int w = tid >> 6, l = tid & 63;
    int row0 = blockIdx.y * BM, col0 = blockIdx.x * BN;
    int wr = (w >> 2) * 64, wc = (w & 3) * 32;
    int crow = (l >> 4) * 4, ccol = l & 15;

    bf16x8 w4f;
    {
        s16x8 tmp;
#pragma unroll
        for (int kk = 0; kk < 8; ++kk) {
            int gk = col0 + (w & 3) * 32 + ((l >> 4) << 3) + kk;
            float v = (ccol < 10 && gk < 2000) ? 0.5f * W4[(size_t)gk * 10 + ccol] : 0.f;
            tmp[kk] = (short)f2bf(v);
        }
        w4f = as_bf(tmp);
    }

    // T14: issue tra3 tile loads before the K-loop (used in epilogue B)
    float4 tpre[8];
    {
        int r_off = tid >> 5;
        int c4 = (tid & 31) * 4;
#pragma unroll
        for (int p = 0; p < 8; ++p) {
            int rl = p * 16 + r_off;
            int gr = row0 + rl;
            int gcb = col0 + c4;
            if (gr < M && gcb + 3 < 2000)
                tpre[p] = *(const float4*)(T + (size_t)gr * 2000 + gcb);
            else
                tpre[p] = make_float4(0.f, 0.f, 0.f, 0.f);
        }
    }

    f32x4 acc[4][2] = {};
    int arow_off = w * 8 + (l >> 3);
    int acol = (((l & 7) ^ (l >> 3)) << 3);

    KLOOP_PIPELINED();

    ushort* actS = lds;

    __syncthreads();
#pragma unroll
    for (int m = 0; m < 4; ++m)
#pragma unroll
        for (int n = 0; n < 2; ++n) {
            int cl = wc + n * 16 + ccol;
            int cch = cl >> 3, clo = cl & 7;
#pragma unroll
            for (int r = 0; r < 4; ++r) {
                int rl = wr + m * 16 + crow + r;
                actS[rl * 128 + (((cch ^ (rl & 7)) << 3) | clo)] = f2bf(fmaxf(acc[m][n][r], 0.f));
            }
        }
    __syncthreads();

    f32x4 acc2[4] = {};
    {
        int chunk = (w & 3) * 4 + (l >> 4);
#pragma unroll
        for (int m = 0; m < 4; ++m) {
            int row = wr + m * 16 + ccol;
            bf16x8 af = as_bf(*(const s16x8*)&actS[row * 128 + ((chunk ^ (row & 7)) << 3)]);
            acc2[m] = __builtin_amdgcn_mfma_f32_16x16x32_bf16(af, w4f, acc2[m], 0, 0, 0);
        }
    }
    __syncthreads();

    // epilogue B: prefetched tra3 tile -> actS (pure cvt+store)
    {
        int r_off = tid >> 5;
        int chunk = (tid & 31) >> 1;
        int lo = (tid & 1) * 4;
#pragma unroll
        for (int p = 0; p < 8; ++p) {
            int rl = p * 16 + r_off;
            float4 tv = tpre[p];
            ushort4 h = { f2bf(tv.x), f2bf(tv.y), f2bf(tv.z), f2bf(tv.w) };
            *(ushort4*)&actS[rl * 128 + ((chunk ^ (rl & 7)) << 3) + lo] = h;
        }
    }
    __syncthreads();

    {
        int chunk = (w & 3) * 4 + (l >> 4);
#pragma unroll
        for (int m = 0; m < 4; ++m) {
            int row = wr + m * 16 + ccol;
            bf16x8 af = as_bf(*(const s16x8*)&actS[row * 128 + ((chunk ^ (row & 7)) << 3)]);
            acc2[m] = __builtin_amdgcn_mfma_f32_16x16x32_bf16(af, w4f, acc2[m], 0, 0, 0);
        }
    }
    __syncthreads();

    float* redS = (float*)lds;   // [4][128][16]
    {
        int q = w & 3;
#pragma unroll
        for (int m = 0; m < 4; ++m)
#pragma unroll
            for (int r = 0; r < 4; ++r) {
                int row = wr + m * 16 + crow + r;
                redS[(q * 128 + row) * 16 + ccol] = acc2[m][r];
            }
    }
    __syncthreads();
    {
        float* dst = sup4p + (size_t)blockIdx.x * ((size_t)M * 10);
#pragma unroll
        for (int p = 0; p < 4; ++p) {
            int o = p * 512 + tid;
            int row = o >> 4, col = o & 15;
            int gr = row0 + row;
            if (col < 10 && gr < M) {
                float s = redS[(0 * 128 + row) * 16 + col] + redS[(1 * 128 + row) * 16 + col]
                        + redS[(2 * 128 + row) * 16 + col] + redS[(3 * 128 + row) * 16 + col];
                dst[(size_t)gr * 10 + col] = s;
            }
        }
    }
}

// ---------------- sum 16 partial slots -> sup4 ----------------
__global__ __launch_bounds__(256) void sup4_reduce(const float* __restrict__ P,
                                                   float* __restrict__ O, int n) {
    int i = blockIdx.x * 256 + threadIdx.x;
    if (i >= n) return;
    float s = 0.f;
#pragma unroll
    for (int j = 0; j < 16; ++j) s += P[(size_t)j * n + i];
    O[i] = s;
}

// ---------------- conversions ----------------
__global__ __launch_bounds__(256) void cvt4(const float* __restrict__ s,
                                            ushort* __restrict__ d, long n4) {
    long i = (long)blockIdx.x * 256 + threadIdx.x;
    if (i >= n4) return;
    float4 v = ((const float4*)s)[i];
    ushort4 o = { f2bf(v.x), f2bf(v.y), f2bf(v.z), f2bf(v.w) };
    ((ushort4*)d)[i] = o;
}

// Fused W1/W2/W3 -> Wt[3072][512] (Wt1 rows [0,512), Wt2 [512,1024), Wt3 [1024,3072))
__global__ __launch_bounds__(256) void cvt_wt3(const float* __restrict__ W1,
                                               const float* __restrict__ W2,
                                               const float* __restrict__ W3,
                                               ushort* __restrict__ Wt) {
    int i = blockIdx.x * 256 + threadIdx.x;
    if (i >= 3072 * 512) return;
    int n = i >> 9, k = i & 511;
    float v = 0.f;
    if (n < 512)       { if (n < 500 && k < 512) v = W1[(size_t)k * 500 + n]; }
    else if (n < 1024) { int nn = n - 512;  if (nn < 500 && k < 500) v = W2[(size_t)k * 500 + nn]; }
    else               { int nn = n - 1024; if (nn < 2000 && k < 500) v = W3[(size_t)k * 2000 + nn]; }
    Wt[i] = f2bf(v);
}

// ---------------- CSR build: count / scan / fill (packed 4B edges) ----------------
__global__ __launch_bounds__(256) void csr_count(const int* __restrict__ rows,
                                                 int* __restrict__ cnt, int E) {
    int e = blockIdx.x * 256 + threadIdx.x;
    if (e < E) atomicAdd(&cnt[rows[e]], 1);
}

__global__ __launch_bounds__(256) void scan1(const int* __restrict__ cnt,
                                             int* __restrict__ csum, int n) {
    __shared__ int red[256];
    int base = blockIdx.x * SCAN_CHUNK;
    int t = threadIdx.x;
    int s = 0;
    if (base + t < n) s += cnt[base + t];
    if (base + t + 256 < n) s += cnt[base + t + 256];
    red[t] = s;
    __syncthreads();
    for (int off = 128; off; off >>= 1) {
        if (t < off) red[t] += red[t + off];
        __syncthreads();
    }
    if (t == 0) csum[blockIdx.x] = red[0];
}

__global__ void scan2(int* csum, int nch) {
    if (threadIdx.x == 0 && blockIdx.x == 0) {
        int acc = 0;
        for (int i = 0; i < nch; ++i) { int v = csum[i]; csum[i] = acc; acc += v; }
    }
}

// also writes cur[] (= rowptr value) so the fill kernel can bump it directly
__global__ __launch_bounds__(256) void scan3(const int* __restrict__ cnt,
                                             const int* __restrict__ csum,
                                             int* __restrict__ rowptr,
                                             int* __restrict__ cur, int n, int E) {
    __shared__ int sm[SCAN_CHUNK];
    int base = blockIdx.x * SCAN_CHUNK;
    int t = threadIdx.x;
    for (int i = t; i < SCAN_CHUNK; i += 256) sm[i] = (base + i < n) ? cnt[base + i] : 0;
    __syncthreads();
    for (int off = 1; off < SCAN_CHUNK; off <<= 1) {
        int i0 = t, i1 = t + 256;
        int v0 = (i0 >= off) ? sm[i0 - off] : 0;
        int v1 = (i1 >= off) ? sm[i1 - off] : 0;
        __syncthreads();
        sm[i0] += v0;
        sm[i1] += v1;
        __syncthreads();
    }
    int off0 = csum[blockIdx.x];
    for (int i = t; i < SCAN_CHUNK; i += 256)
        if (base + i < n) {
            int v = off0 + (i ? sm[i - 1] : 0);
            rowptr[base + i] = v;
            cur[base + i] = v;
        }
    if (blockIdx.x == 0 && t == 0) rowptr[n] = E;
}

// edge packed as (bf16(val) << 16) | col   [col < 65536]
__global__ __launch_bounds__(256) void csr_fill(const int* __restrict__ rows,
                                                const int* __restrict__ cols,
                                                const float* __restrict__ vals,
                                                int* __restrict__ cur,
                                                uint* __restrict__ edges, int E) {
    int e = blockIdx.x * 256 + threadIdx.x;
    if (e >= E) return;
    int p = atomicAdd(&cur[rows[e]], 1);
    edges[p] = ((uint)f2bf(vals[e]) << 16) | (uint)cols[e];
}

// ---------------- D-sliced SpMM gather, GROUP-PER-ROW, packed edges, 8-edge unroll ---
__global__ __launch_bounds__(256) void spmm_bfs(const int* __restrict__ rowptr,
                                                const uint* __restrict__ edges,
                                                const ushort* __restrict__ S,
                                                const float* __restrict__ T,
                                                ushort* __restrict__ O,
                                                int nrows, int domix) {
    int row = (int)((blockIdx.x * 256 + threadIdx.x) >> 3);
    if (row >= nrows) return;
    int t = threadIdx.x & 7;
    int c0 = blockIdx.y * 64 + t * 8;
    int beg = rowptr[row], end = rowptr[row + 1];
    const ushort* Sc = S + c0;

    float acc[8] = {0.f, 0.f, 0.f, 0.f, 0.f, 0.f, 0.f, 0.f};
    int e = beg;
    for (; e + 7 < end; e += 8) {
        uint ep[8];
#pragma unroll
        for (int q = 0; q < 8; ++q) ep[q] = edges[e + q];
        s16x8 sv[8];
#pragma unroll
        for (int q = 0; q < 8; ++q)
            sv[q] = *(const s16x8*)(Sc + (size_t)(ep[q] & 0xFFFFu) * 512);
#pragma unroll
        for (int q = 0; q < 8; ++q) {
            float v = bf2f((ushort)(ep[q] >> 16));
#pragma unroll
            for (int j = 0; j < 8; ++j)
                acc[j] += v * bf2f((ushort)sv[q][j]);
        }
    }
    for (; e + 3 < end; e += 4) {
        uint e0 = edges[e], e1 = edges[e + 1], e2 = edges[e + 2], e3 = edges[e + 3];
        float v0 = bf2f((ushort)(e0 >> 16)), v1 = bf2f((ushort)(e1 >> 16));
        float v2 = bf2f((ushort)(e2 >> 16)), v3 = bf2f((ushort)(e3 >> 16));
        s16x8 a = *(const s16x8*)(Sc + (size_t)(e0 & 0xFFFFu) * 512);
        s16x8 b = *(const s16x8*)(Sc + (size_t)(e1 & 0xFFFFu) * 512);
        s16x8 c = *(const s16x8*)(Sc + (size_t)(e2 & 0xFFFFu) * 512);
        s16x8 d = *(const s16x8*)(Sc + (size_t)(e3 & 0xFFFFu) * 512);
#pragma unroll
        for (int j = 0; j < 8; ++j)
            acc[j] += v0 * bf2f((ushort)a[j]) + v1 * bf2f((ushort)b[j])
                    + v2 * bf2f((ushort)c[j]) + v3 * bf2f((ushort)d[j]);
    }
    for (; e < end; ++e) {
        uint e0 = edges[e];
        float v0 = bf2f((ushort)(e0 >> 16));
        s16x8 a = *(const s16x8*)(Sc + (size_t)(e0 & 0xFFFFu) * 512);
#pragma unroll
        for (int j = 0; j < 8; ++j)
            acc[j] += v0 * bf2f((ushort)a[j]);
    }

    float res[8];
    if (domix) {
        float tv[8] = {0.f, 0.f, 0.f, 0.f, 0.f, 0.f, 0.f, 0.f};
        const float* trow = T + (size_t)row * 500;
        if (c0 + 8 <= 500) {
            float4 t0 = *(const float4*)(trow + c0);
            float4 t1 = *(const float4*)(trow + c0 + 4);
            tv[0] = t0.x; tv[1] = t0.y; tv[2] = t0.z; tv[3] = t0.w;
            tv[4] = t1.x; tv[5] = t1.y; tv[6] = t1.z; tv[7] = t1.w;
        } else {
#pragma unroll
            for (int j = 0; j < 8; ++j)
                if (c0 + j < 500) tv[j] = trow[c0 + j];
        }
#pragma unroll
        for (int j = 0; j < 8; ++j)
            res[j] = (c0 + j < 500) ? (0.5f * fmaxf(acc[j], 0.f) + 0.5f * tv[j]) : 0.f;
    } else {
#pragma unroll
        for (int j = 0; j < 8; ++j)
            res[j] = (c0 + j < 500) ? acc[j] : 0.f;
    }
    s16x8 o;
#pragma unroll
    for (int j = 0; j < 8; ++j) o[j] = (short)f2bf(res[j]);
    *(s16x8*)(O + (size_t)row * 512 + c0) = o;
}

// ---------------- SpMM gather, D=10 f32, packed edges; optional mix+@W5 epilogue -----
__global__ __launch_bounds__(256) void spmm10(const int* __restrict__ rowptr,
                                              const uint* __restrict__ edges,
                                              const float* __restrict__ S,
                                              const float* __restrict__ T,
                                              const float* __restrict__ W5,
                                              float* __restrict__ O, int nrows) {
    int g = (int)((blockIdx.x * 256 + threadIdx.x) >> 4);
    int t = threadIdx.x & 15;
    if (g >= nrows || t >= 10) return;
    int beg = rowptr[g], end = rowptr[g + 1];
    float acc = 0.f;
    for (int e = beg; e < end; ++e) {
        uint ed = edges[e];
        acc += bf2f((ushort)(ed >> 16)) * S[(size_t)(ed & 0xFFFFu) * 10 + t];
    }
    if (W5) {
        float m = 0.5f * fmaxf(acc, 0.f) + 0.5f * T[(size_t)g * 10 + t];
        float s5 = 0.f;
#pragma unroll
        for (int i = 0; i < 10; ++i)
            s5 += __shfl(m, i, 16) * W5[i * 10 + t];
        O[(size_t)g * 10 + t] = s5;
    } else {
        O[(size_t)g * 10 + t] = acc;
    }
}

extern "C" void kernel_launch(void* const* d_in, const int* in_sizes, int n_in,
                              void* d_out, int out_size, void* d_ws, size_t ws_size,
                              hipStream_t stream) {
    const float* x    = (const float*)d_in[0];
    const int*   ar   = (const int*)d_in[1];
    const int*   ac   = (const int*)d_in[2];
    const float* av   = (const float*)d_in[3];
    const float* tra1 = (const float*)d_in[4];
    const float* tra2 = (const float*)d_in[5];
    const float* tra3 = (const float*)d_in[6];
    const float* z    = (const float*)d_in[7];
    const float* W1   = (const float*)d_in[8];
    const float* W2   = (const float*)d_in[9];
    const float* W3   = (const float*)d_in[10];
    const float* W4   = (const float*)d_in[11];
    const float* W5   = (const float*)d_in[12];

    const int E = in_sizes[1];
    const int N = in_sizes[7] / 10;   // 50000 (< 65536 -> u16 col packing valid)
    const int NCH = (N + SCAN_CHUNK - 1) / SCAN_CHUNK;

    ushort* Abf    = (ushort*)d_ws;                     // [N,512] bf16
    ushort* Sbf    = Abf + (size_t)N * 512;             // [N,512] bf16
    ushort* Wt1    = Sbf + (size_t)N * 512;             // [512,512] bf16
    ushort* Wt2    = Wt1 + 512 * 512;                   // [512,512] bf16
    ushort* Wt3    = Wt2 + 512 * 512;                   // [2048,512] bf16
    float*  sup4   = (float*)(Wt3 + 2048 * 512);        // [N,10] f32
    float*  sup5   = sup4 + (size_t)N * 10;             // [N,10] f32
    float*  sup4p  = sup5 + (size_t)N * 10;             // [16][N*10] f32 partials
    uint*   edges  = (uint*)(sup4p + (size_t)16 * N * 10); // [E] packed 4B
    int*    rowptr = (int*)(edges + E);                 // [N+1]
    int*    cnt    = rowptr + (N + 1);                  // [N]
    int*    csum   = cnt + N;                           // [NCH]
    float*  out    = (float*)d_out;

    dim3 blk(256);
    dim3 blk8(512);

    // ---- conversions upfront ----
    cvt4<<<(int)(((long)N * 512 / 4 + 255) / 256), blk, 0, stream>>>(x, Abf, (long)N * 512 / 4);
    cvt_wt3<<<(3072 * 512 + 255) / 256, blk, 0, stream>>>(W1, W2, W3, Wt1);

    // ---- CSR build ----
    hipMemsetAsync(cnt, 0, (size_t)N * sizeof(int), stream);
    csr_count<<<(E + 255) / 256, blk, 0, stream>>>(ar, cnt, E);
    scan1<<<NCH, blk, 0, stream>>>(cnt, csum, N);
    scan2<<<1, 64, 0, stream>>>(csum, NCH);
    scan3<<<NCH, blk, 0, stream>>>(cnt, csum, rowptr, cnt, N, E);   // cnt becomes cur[]
    csr_fill<<<(E + 255) / 256, blk, 0, stream>>>(ar, ac, av, cnt, edges, E);

    dim3 spmm_grid((N * 8 + 255) / 256, NSLICE);
    const int spmm10_blocks = (N * 16 + 255) / 256;

    // ---- Layer 1: Sbf = Abf@W1t; Abf = mix(spmm(Sbf), tra1)
    {
        dim3 g(4, (N + BM - 1) / BM);
        gemm_sup<<<g, blk8, 0, stream>>>(Abf, Wt1, Sbf, N);
    }
    spmm_bfs<<<spmm_grid, blk, 0, stream>>>(rowptr, edges, Sbf, tra1, Abf, N, 1);

    // ---- Layer 2: Sbf = Abf@W2t; Abf(m2) = mix(spmm(Sbf), tra2)
    {
        dim3 g(4, (N + BM - 1) / BM);
        gemm_sup<<<g, blk8, 0, stream>>>(Abf, Wt2, Sbf, N);
    }
    spmm_bfs<<<spmm_grid, blk, 0, stream>>>(rowptr, edges, Sbf, tra2, Abf, N, 1);

    // ---- Layer 3 (spmm-first, fused): Sbf(g) = spmm(m2) raw;
    //      sup4p[16 slots] = (relu(g@W3)+tra3)@(0.5*W4) partials; sup4 = sum
    spmm_bfs<<<spmm_grid, blk, 0, stream>>>(rowptr, edges, Abf, nullptr, Sbf, N, 0);
    {
        dim3 g(16, (N + BM - 1) / BM);
        gemm3_w4<<<g, blk8, 0, stream>>>(Sbf, Wt3, tra3, W4, sup4p, N);
    }
    sup4_reduce<<<(N * 10 + 255) / 256, blk, 0, stream>>>(sup4p, sup4, N * 10);

    // ---- Layer 4+5a: sup5 = (mix(spmm(sup4), z)) @ W5  (fused epilogue)
    spmm10<<<spmm10_blocks, blk, 0, stream>>>(rowptr, edges, sup4, z, W5, sup5, N);

    // ---- Layer 5b: out = spmm(sup5) raw
    spmm10<<<spmm10_blocks, blk, 0, stream>>>(rowptr, edges, sup5, nullptr, nullptr, out, N);
}